// Round 2
// baseline (3574.344 us; speedup 1.0000x reference)
//
#include <hip/hip_runtime.h>
#include <hip/hip_bf16.h>

typedef __hip_bfloat16 bf16;
typedef unsigned short u16t;
typedef unsigned int u32t;

#define HH 384
#define WW 384
#define HWH 147456
#define EPSV 1e-6f

__device__ __forceinline__ float bflo(u32t p) {
  union { u32t i; float f; } x; x.i = p << 16; return x.f;
}
__device__ __forceinline__ float bfhi(u32t p) {
  union { u32t i; float f; } x; x.i = p & 0xffff0000u; return x.f;
}

// ---------------- prep: per-patch aggregated weights ----------------
// grid = 72 patches * 8 chunks, 256 threads. All inputs f32.
__global__ __launch_bounds__(256) void k_prep(
    const float* __restrict__ v,
    const float* __restrict__ w1, const float* __restrict__ b1,
    const float* __restrict__ w2, const float* __restrict__ b2,
    const float* __restrict__ w3, const float* __restrict__ b3,
    const float* __restrict__ wsca, const float* __restrict__ bsca,
    const float* __restrict__ w4, const float* __restrict__ b4,
    const float* __restrict__ w5, const float* __restrict__ b5,
    float* __restrict__ aw1, float* __restrict__ a4f, float* __restrict__ ascaf,
    float* __restrict__ a3f, float* __restrict__ a5f,
    float* __restrict__ ab1, float* __restrict__ ab2, float* __restrict__ ab4,
    float* __restrict__ abscaf, float* __restrict__ ab3, float* __restrict__ ab5,
    bf16* __restrict__ aw2) {
  int bid = blockIdx.x;
  int n = bid >> 3, sc = bid & 7;
  int b = n / 36, ph = (n % 36) / 6, pw = n % 6;
  float vr[5];
#pragma unroll
  for (int k = 0; k < 5; ++k) vr[k] = v[((b*5 + k)*6 + ph)*6 + pw];
  int t = threadIdx.x;
  // aw1 [128][64], a4 [128][64]
  for (int j = sc*1024 + t; j < sc*1024 + 1024; j += 256) {
    float s1 = 0.f, s4 = 0.f;
#pragma unroll
    for (int k = 0; k < 5; ++k) {
      s1 += vr[k] * w1[k*8192 + j];
      s4 += vr[k] * w4[k*8192 + j];
    }
    aw1[n*8192 + j] = s1;
    a4f[n*8192 + j] = s4;
  }
  // asca, a3, a5: [64][64]
  for (int j = sc*512 + t; j < sc*512 + 512; j += 256) {
    float ss = 0.f, s3 = 0.f, s5 = 0.f;
#pragma unroll
    for (int k = 0; k < 5; ++k) {
      ss += vr[k] * wsca[k*4096 + j];
      s3 += vr[k] * w3[k*4096 + j];
      s5 += vr[k] * w5[k*4096 + j];
    }
    ascaf[n*4096 + j] = ss;
    a3f[n*4096 + j] = s3;
    a5f[n*4096 + j] = s5;
  }
  if (sc == 0) {
    if (t < 128) {
      float s1 = 0.f, s2 = 0.f, s4 = 0.f;
#pragma unroll
      for (int k = 0; k < 5; ++k) {
        s1 += vr[k] * b1[k*128 + t];
        s2 += vr[k] * b2[k*128 + t];
        s4 += vr[k] * b4[k*128 + t];
      }
      ab1[n*128 + t] = s1; ab2[n*128 + t] = s2; ab4[n*128 + t] = s4;
    } else if (t < 192) {
      int c = t - 128;
      float ss = 0.f, s3 = 0.f, s5 = 0.f;
#pragma unroll
      for (int k = 0; k < 5; ++k) {
        ss += vr[k] * bsca[k*64 + c];
        s3 += vr[k] * b3[k*64 + c];
        s5 += vr[k] * b5[k*64 + c];
      }
      abscaf[n*64 + c] = ss; ab3[n*64 + c] = s3; ab5[n*64 + c] = s5;
    }
  }
  // aw2: read in w2-native order (coalesced), scatter into conv2's LDS-chunk layout:
  // [n][pp 8][icc 8][ic 16][t 9][ocp 16], ocp<8 -> oc=pp*8+ocp (low), else oc=64+pp*8+(ocp-8) (high)
  for (int j = sc*18432 + t; j < sc*18432 + 18432; j += 256) {
    float s = 0.f;
#pragma unroll
    for (int k = 0; k < 5; ++k) s += vr[k] * w2[(size_t)k*147456 + j];
    int oc = j / 1152;
    int rr = j - oc*1152;
    int ii = rr / 9;
    int tt = rr - ii*9;
    int pp, ocp;
    if (oc < 64) { pp = oc >> 3; ocp = oc & 7; }
    else { int o2 = oc - 64; pp = o2 >> 3; ocp = 8 + (o2 & 7); }
    int icc = ii >> 4, ic = ii & 15;
    aw2[(size_t)n*147456 + ((((pp*8 + icc)*16 + ic)*9 + tt)*16 + ocp)] = __float2bfloat16(s);
  }
}

// ---------------- LN + conv1 (1x1, 64->128) ----------------
// grid = B*H*6 = 4608 blocks (one image row-segment of 64 px), 256 threads
__global__ __launch_bounds__(256) void k_ln_conv1(
    const float* __restrict__ inp, const float* __restrict__ aw1,
    const float* __restrict__ ab1, const float* __restrict__ n1w,
    const float* __restrict__ n1b, bf16* __restrict__ x1) {
  __shared__ float wl[8192];
  __shared__ float xl[4096];
  __shared__ float bl[128];
  __shared__ float gl[64], bel[64];
  __shared__ float ps[4][64], ps2[4][64];
  int bid = blockIdx.x;
  int b = bid / 2304; int rem = bid % 2304; int h = rem / 6; int pw = rem % 6;
  int ph = h >> 6; int n = (b*6 + ph)*6 + pw; int w0 = pw*64;
  int t = threadIdx.x;
  for (int j = t; j < 8192; j += 256) wl[j] = aw1[n*8192 + j];
  if (t < 128) bl[t] = ab1[n*128 + t];
  if (t < 64) { gl[t] = n1w[t]; bel[t] = n1b[t]; }
  const float* ip = inp + ((size_t)b*64*HH + h)*WW + w0;
  for (int j = t; j < 4096; j += 256) {
    int c = j >> 6, px = j & 63;
    xl[j] = ip[(size_t)c*HWH + px];
  }
  __syncthreads();
  int px = t & 63, part = t >> 6;
  float s = 0.f, s2 = 0.f;
  for (int c = part*16; c < part*16 + 16; ++c) { float xv = xl[c*64 + px]; s += xv; s2 += xv*xv; }
  ps[part][px] = s; ps2[part][px] = s2;
  __syncthreads();
  float mu = (ps[0][px] + ps[1][px] + ps[2][px] + ps[3][px]) * (1.f/64.f);
  float var = (ps2[0][px] + ps2[1][px] + ps2[2][px] + ps2[3][px]) * (1.f/64.f) - mu*mu;
  float rs = rsqrtf(fmaxf(var, 0.f) + EPSV);
  for (int c = part*16; c < part*16 + 16; ++c)
    xl[c*64 + px] = (xl[c*64 + px] - mu) * rs * gl[c] + bel[c];
  __syncthreads();
  float acc[32];
  int ocb = part*32;
#pragma unroll
  for (int o = 0; o < 32; ++o) acc[o] = bl[ocb + o];
  for (int i4 = 0; i4 < 16; ++i4) {
    float x0 = xl[(i4*4+0)*64 + px], x1v = xl[(i4*4+1)*64 + px];
    float x2v = xl[(i4*4+2)*64 + px], x3v = xl[(i4*4+3)*64 + px];
#pragma unroll
    for (int o = 0; o < 32; ++o) {
      const float4 wv = *(const float4*)&wl[(ocb + o)*64 + i4*4];
      acc[o] += wv.x*x0 + wv.y*x1v + wv.z*x2v + wv.w*x3v;
    }
  }
  bf16* xp = x1 + ((size_t)b*128*HH + h)*WW + w0 + px;
#pragma unroll
  for (int o = 0; o < 32; ++o) xp[(size_t)(ocb + o)*HWH] = __float2bfloat16(acc[o]);
}

// ---------------- conv2 (3x3 patch-local, 128->128) + SG + pool partials ----------------
// grid = 72 patches * 4 row-tiles = 288 blocks, 256 threads; tile = 16 rows x 64 cols
__global__ __launch_bounds__(256) void k_conv2(
    const bf16* __restrict__ x1, const bf16* __restrict__ aw2,
    const float* __restrict__ ab2, bf16* __restrict__ kx, float* __restrict__ pool) {
  __shared__ alignas(16) u16t xt[16][18][68];
  __shared__ alignas(16) float wt[16][9][16];
  __shared__ float pool_l[64];
  int bid = blockIdx.x;
  int n = bid >> 2, tile = bid & 3;
  int b = n / 36, ph = (n % 36) / 6, pw = n % 6;
  int r0 = tile * 16;
  int w0c = pw * 64;
  int t = threadIdx.x;
  if (t < 64) pool_l[t] = 0.0f;
  int row = t >> 4;
  int colb = (t & 15) << 2;
  const u16t* x1b = (const u16t*)x1 + (size_t)b*128*HWH + (size_t)(ph*64)*WW + w0c;
  for (int pp = 0; pp < 8; ++pp) {
    float acc[4][16];
#pragma unroll
    for (int c = 0; c < 4; ++c)
#pragma unroll
      for (int q = 0; q < 16; ++q)
        acc[c][q] = ab2[n*128 + (q < 8 ? pp*8 + q : 64 + pp*8 + (q - 8))];
    for (int icc = 0; icc < 8; ++icc) {
      __syncthreads();
      for (int j = t; j < 18432; j += 256) {
        int c = j & 63; int r = (j >> 6) % 18; int ic = j / 1152;
        int pr = r0 + r - 1;
        u16t val = 0;
        if (pr >= 0 && pr < 64)
          val = x1b[(size_t)(icc*16 + ic)*HWH + (size_t)pr*WW + c];
        xt[ic][r][1 + c] = val;
      }
      for (int j = t; j < 288; j += 256) {
        int r = j % 18, ic = j / 18;
        xt[ic][r][0] = 0; xt[ic][r][65] = 0; xt[ic][r][66] = 0; xt[ic][r][67] = 0;
      }
      {
        const u16t* wsrc = (const u16t*)aw2 + (size_t)n*147456 + (size_t)(pp*8 + icc)*2304;
        float* wdst = &wt[0][0][0];
        for (int j = t; j < 2304; j += 256) {
          union { u32t i; float f; } xx; xx.i = ((u32t)wsrc[j]) << 16;
          wdst[j] = xx.f;
        }
      }
      __syncthreads();
#pragma unroll 2
      for (int ic = 0; ic < 16; ++ic) {
#pragma unroll
        for (int kh = 0; kh < 3; ++kh) {
          const u16t* xr = &xt[ic][row + kh][colb];
          uint2 aa = *(const uint2*)xr;
          u32t cc = *(const u32t*)(xr + 4);
          float xs[6];
          xs[0] = bflo(aa.x); xs[1] = bfhi(aa.x);
          xs[2] = bflo(aa.y); xs[3] = bfhi(aa.y);
          xs[4] = bflo(cc);   xs[5] = bfhi(cc);
#pragma unroll
          for (int kw = 0; kw < 3; ++kw) {
            const float* wr = &wt[ic][kh*3 + kw][0];
            float4 wa = *(const float4*)(wr + 0);
            float4 wb = *(const float4*)(wr + 4);
            float4 wc = *(const float4*)(wr + 8);
            float4 wd = *(const float4*)(wr + 12);
#pragma unroll
            for (int c = 0; c < 4; ++c) {
              float xv = xs[c + kw];
              acc[c][0]  += wa.x*xv; acc[c][1]  += wa.y*xv;
              acc[c][2]  += wa.z*xv; acc[c][3]  += wa.w*xv;
              acc[c][4]  += wb.x*xv; acc[c][5]  += wb.y*xv;
              acc[c][6]  += wb.z*xv; acc[c][7]  += wb.w*xv;
              acc[c][8]  += wc.x*xv; acc[c][9]  += wc.y*xv;
              acc[c][10] += wc.z*xv; acc[c][11] += wc.w*xv;
              acc[c][12] += wd.x*xv; acc[c][13] += wd.y*xv;
              acc[c][14] += wd.z*xv; acc[c][15] += wd.w*xv;
            }
          }
        }
      }
    }
    // SimpleGate + write keep_x (bf16) + pool partial sums
    float psum[8];
#pragma unroll
    for (int q = 0; q < 8; ++q) psum[q] = 0.f;
    int hh = ph*64 + r0 + row;
#pragma unroll
    for (int c = 0; c < 4; ++c) {
      int ww = w0c + colb + c;
#pragma unroll
      for (int q = 0; q < 8; ++q) {
        float kv = acc[c][q] * acc[c][8 + q];
        kx[((size_t)(b*64 + pp*8 + q)*HH + hh)*WW + ww] = __float2bfloat16(kv);
        psum[q] += kv;
      }
    }
#pragma unroll
    for (int q = 0; q < 8; ++q) {
      float vsum = psum[q];
      for (int off = 32; off > 0; off >>= 1) vsum += __shfl_down(vsum, off);
      if ((t & 63) == 0) atomicAdd(&pool_l[pp*8 + q], vsum);
    }
  }
  __syncthreads();
  if (t < 64) atomicAdd(&pool[b*64 + t], pool_l[t]);
}

// ---------------- post1: sca conv, pooled-mul, w3 conv, y = inp + x*beta ----------------
// grid 4608, 256 threads (row-segment of 64 px)
__global__ __launch_bounds__(256) void k_post1(
    const bf16* __restrict__ kxg, const float* __restrict__ inp,
    const float* __restrict__ pool,
    const float* __restrict__ ascaf, const float* __restrict__ abscaf,
    const float* __restrict__ a3f, const float* __restrict__ ab3,
    const float* __restrict__ beta, float* __restrict__ yws) {
  __shared__ float wA[4096];
  __shared__ float wB[4096];
  __shared__ float bufA[4096];
  __shared__ float bufB[4096];
  __shared__ float bsl[64], b3l[64], pol[64], betal[64];
  int bid = blockIdx.x;
  int b = bid / 2304; int rem = bid % 2304; int h = rem / 6; int pw = rem % 6;
  int ph = h >> 6; int n = (b*6 + ph)*6 + pw; int w0 = pw*64;
  int t = threadIdx.x;
  for (int j = t; j < 4096; j += 256) { wA[j] = ascaf[n*4096 + j]; wB[j] = a3f[n*4096 + j]; }
  if (t < 64) {
    bsl[t] = abscaf[n*64 + t];
    b3l[t] = ab3[n*64 + t];
    pol[t] = pool[b*64 + t] * (1.0f/147456.0f);
    betal[t] = beta[t];
  }
  const bf16* kxp = kxg + ((size_t)b*64*HH + h)*WW + w0;
  for (int j = t; j < 4096; j += 256) {
    int c = j >> 6, px = j & 63;
    bufA[j] = __bfloat162float(kxp[(size_t)c*HWH + px]);
  }
  __syncthreads();
  int px = t & 63, part = t >> 6;
  int ob = part*16;
  float acc[16];
#pragma unroll
  for (int o = 0; o < 16; ++o) acc[o] = bsl[ob + o];
  for (int i4 = 0; i4 < 16; ++i4) {
    float x0 = bufA[(i4*4+0)*64 + px], x1v = bufA[(i4*4+1)*64 + px];
    float x2v = bufA[(i4*4+2)*64 + px], x3v = bufA[(i4*4+3)*64 + px];
#pragma unroll
    for (int o = 0; o < 16; ++o) {
      const float4 wv = *(const float4*)&wA[(ob + o)*64 + i4*4];
      acc[o] += wv.x*x0 + wv.y*x1v + wv.z*x2v + wv.w*x3v;
    }
  }
#pragma unroll
  for (int o = 0; o < 16; ++o) bufB[(ob + o)*64 + px] = pol[ob + o] * acc[o];
  __syncthreads();
#pragma unroll
  for (int o = 0; o < 16; ++o) acc[o] = b3l[ob + o];
  for (int i4 = 0; i4 < 16; ++i4) {
    float x0 = bufB[(i4*4+0)*64 + px], x1v = bufB[(i4*4+1)*64 + px];
    float x2v = bufB[(i4*4+2)*64 + px], x3v = bufB[(i4*4+3)*64 + px];
#pragma unroll
    for (int o = 0; o < 16; ++o) {
      const float4 wv = *(const float4*)&wB[(ob + o)*64 + i4*4];
      acc[o] += wv.x*x0 + wv.y*x1v + wv.z*x2v + wv.w*x3v;
    }
  }
  const float* inpp = inp + ((size_t)b*64*HH + h)*WW + w0;
  float* yp = yws + ((size_t)b*64*HH + h)*WW + w0;
#pragma unroll
  for (int o = 0; o < 16; ++o) {
    int c = ob + o;
    yp[(size_t)c*HWH + px] = inpp[(size_t)c*HWH + px] + acc[o]*betal[c];
  }
}

// ---------------- post2: LN(y), w4, SG, w5, out = y + x*gamma ----------------
// grid 4608, 256 threads. yws aliases d_out (block-private tiles: read-then-overwrite safe)
__global__ __launch_bounds__(256) void k_post2(
    const float* __restrict__ yws,
    const float* __restrict__ a4f, const float* __restrict__ ab4,
    const float* __restrict__ a5f, const float* __restrict__ ab5,
    const float* __restrict__ n2w, const float* __restrict__ n2b,
    const float* __restrict__ gamma, float* __restrict__ outp) {
  __shared__ float w4l[8192];
  __shared__ alignas(16) u16t w5l[4096];
  __shared__ float yb[4096];
  __shared__ float lnb[4096];
  __shared__ float ps[4][64], ps2[4][64];
  __shared__ float b4l[128], b5l[64], gl[64], bel[64], gml[64];
  int bid = blockIdx.x;
  int b = bid / 2304; int rem = bid % 2304; int h = rem / 6; int pw = rem % 6;
  int ph = h >> 6; int n = (b*6 + ph)*6 + pw; int w0 = pw*64;
  int t = threadIdx.x;
  for (int j = t; j < 8192; j += 256) w4l[j] = a4f[n*8192 + j];
  for (int j = t; j < 4096; j += 256) {
    bf16 hbits = __float2bfloat16(a5f[n*4096 + j]);
    w5l[j] = *reinterpret_cast<u16t*>(&hbits);
  }
  if (t < 128) b4l[t] = ab4[n*128 + t];
  if (t < 64) {
    b5l[t] = ab5[n*64 + t];
    gl[t]  = n2w[t];
    bel[t] = n2b[t];
    gml[t] = gamma[t];
  }
  const float* yp = yws + ((size_t)b*64*HH + h)*WW + w0;
  for (int j = t; j < 4096; j += 256) {
    int c = j >> 6, px = j & 63;
    yb[j] = yp[(size_t)c*HWH + px];
  }
  __syncthreads();
  int px = t & 63, part = t >> 6;
  float s = 0.f, s2 = 0.f;
  for (int c = part*16; c < part*16 + 16; ++c) { float yv = yb[c*64 + px]; s += yv; s2 += yv*yv; }
  ps[part][px] = s; ps2[part][px] = s2;
  __syncthreads();
  float mu = (ps[0][px] + ps[1][px] + ps[2][px] + ps[3][px]) * (1.f/64.f);
  float var = (ps2[0][px] + ps2[1][px] + ps2[2][px] + ps2[3][px]) * (1.f/64.f) - mu*mu;
  float rs = rsqrtf(fmaxf(var, 0.f) + EPSV);
  for (int c = part*16; c < part*16 + 16; ++c)
    lnb[c*64 + px] = (yb[c*64 + px] - mu) * rs * gl[c] + bel[c];
  __syncthreads();
  // w4 (64->128) + SimpleGate fused: part handles keep-channels qb..qb+15
  int qb = part*16;
  float sL[16], sH[16];
#pragma unroll
  for (int q = 0; q < 16; ++q) { sL[q] = b4l[qb + q]; sH[q] = b4l[64 + qb + q]; }
  for (int i4 = 0; i4 < 16; ++i4) {
    float x0 = lnb[(i4*4+0)*64 + px], x1v = lnb[(i4*4+1)*64 + px];
    float x2v = lnb[(i4*4+2)*64 + px], x3v = lnb[(i4*4+3)*64 + px];
#pragma unroll
    for (int q = 0; q < 16; ++q) {
      const float4 wL = *(const float4*)&w4l[(qb + q)*64 + i4*4];
      sL[q] += wL.x*x0 + wL.y*x1v + wL.z*x2v + wL.w*x3v;
      const float4 wH = *(const float4*)&w4l[(64 + qb + q)*64 + i4*4];
      sH[q] += wH.x*x0 + wH.y*x1v + wH.z*x2v + wH.w*x3v;
    }
  }
  __syncthreads();
#pragma unroll
  for (int q = 0; q < 16; ++q) lnb[(qb + q)*64 + px] = sL[q]*sH[q];
  __syncthreads();
  // w5 (64->64)
  int ob = qb;
  float acc[16];
#pragma unroll
  for (int o = 0; o < 16; ++o) acc[o] = b5l[ob + o];
  for (int i4 = 0; i4 < 16; ++i4) {
    float x0 = lnb[(i4*4+0)*64 + px], x1v = lnb[(i4*4+1)*64 + px];
    float x2v = lnb[(i4*4+2)*64 + px], x3v = lnb[(i4*4+3)*64 + px];
#pragma unroll
    for (int o = 0; o < 16; ++o) {
      uint2 wp = *(const uint2*)&w5l[(ob + o)*64 + i4*4];
      acc[o] += bflo(wp.x)*x0 + bfhi(wp.x)*x1v + bflo(wp.y)*x2v + bfhi(wp.y)*x3v;
    }
  }
  float* op = outp + ((size_t)b*64*HH + h)*WW + w0;
#pragma unroll
  for (int o = 0; o < 16; ++o) {
    int c = ob + o;
    op[(size_t)c*HWH + px] = yb[c*64 + px] + acc[o]*gml[c];
  }
}

extern "C" void kernel_launch(void* const* d_in, const int* in_sizes, int n_in,
                              void* d_out, int out_size, void* d_ws, size_t ws_size,
                              hipStream_t stream) {
  (void)in_sizes; (void)n_in; (void)out_size; (void)ws_size;
  const float* inp  = (const float*)d_in[0];
  const float* v    = (const float*)d_in[1];
  const float* w1   = (const float*)d_in[2];
  const float* b1   = (const float*)d_in[3];
  const float* w2   = (const float*)d_in[4];
  const float* b2   = (const float*)d_in[5];
  const float* w3   = (const float*)d_in[6];
  const float* b3   = (const float*)d_in[7];
  const float* wsca = (const float*)d_in[8];
  const float* bsca = (const float*)d_in[9];
  const float* w4   = (const float*)d_in[10];
  const float* b4   = (const float*)d_in[11];
  const float* w5   = (const float*)d_in[12];
  const float* b5   = (const float*)d_in[13];
  const float* n1w  = (const float*)d_in[14];
  const float* n1b  = (const float*)d_in[15];
  const float* n2w  = (const float*)d_in[16];
  const float* n2b  = (const float*)d_in[17];
  const float* beta = (const float*)d_in[18];
  const float* gamma= (const float*)d_in[19];

  // workspace layout: fp32 aggregated region (8.4 MB), then bf16 buffers. ~143 MB total.
  float* wsf  = (float*)d_ws;
  float* pool = wsf;                    // [2][64]
  float* aw1  = wsf + 128;              // [72][128][64]
  float* a4f  = aw1 + 589824;           // [72][128][64]
  float* ascaf= a4f + 589824;           // [72][64][64]
  float* a3f  = ascaf + 294912;         // [72][64][64]
  float* a5f  = a3f + 294912;           // [72][64][64]
  float* ab1  = a5f + 294912;           // [72][128]
  float* ab2  = ab1 + 9216;
  float* ab4  = ab2 + 9216;
  float* abscaf = ab4 + 9216;           // [72][64]
  float* ab3  = abscaf + 4608;
  float* ab5  = ab3 + 4608;
  bf16* aw2   = (bf16*)(ab5 + 4608);    // [72][147456] bf16
  bf16* x1    = aw2 + 10616832;         // [2][128][384][384] bf16
  bf16* kxb   = x1 + 37748736;          // keep_x bf16 [2][64][384][384]
  float* out0 = (float*)d_out;
  float* yws  = out0;                   // y aliases d_out (block-private read-then-write)

  hipMemsetAsync(pool, 0, 128*sizeof(float), stream);
  k_prep<<<dim3(576), dim3(256), 0, stream>>>(v, w1, b1, w2, b2, w3, b3, wsca, bsca,
      w4, b4, w5, b5, aw1, a4f, ascaf, a3f, a5f, ab1, ab2, ab4, abscaf, ab3, ab5, aw2);
  k_ln_conv1<<<dim3(4608), dim3(256), 0, stream>>>(inp, aw1, ab1, n1w, n1b, x1);
  k_conv2<<<dim3(288), dim3(256), 0, stream>>>(x1, aw2, ab2, kxb, pool);
  k_post1<<<dim3(4608), dim3(256), 0, stream>>>(kxb, inp, pool, ascaf, abscaf, a3f, ab3, beta, yws);
  k_post2<<<dim3(4608), dim3(256), 0, stream>>>(yws, a4f, ab4, a5f, ab5, n2w, n2b, gamma, out0);
  // output 1: v pass-through (f32, 360 elements)
  hipMemcpyAsync((char*)d_out + (size_t)18874368*4, d_in[1], 360*4,
                 hipMemcpyDeviceToDevice, stream);
}

// Round 4
// 850.815 us; speedup vs baseline: 4.2011x; 4.2011x over previous
//
#include <hip/hip_runtime.h>
#include <hip/hip_bf16.h>

typedef __hip_bfloat16 bf16;
typedef unsigned short u16t;
typedef unsigned int u32t;
typedef __attribute__((ext_vector_type(8))) short short8;
typedef __attribute__((ext_vector_type(4))) float f32x4;

#define HH 384
#define WW 384
#define HWH 147456
#define EPSV 1e-6f

__device__ __forceinline__ float bflo(u32t p) {
  union { u32t i; float f; } x; x.i = p << 16; return x.f;
}
__device__ __forceinline__ float bfhi(u32t p) {
  union { u32t i; float f; } x; x.i = p & 0xffff0000u; return x.f;
}

// ---------------- prep: per-patch aggregated weights ----------------
// grid = 72 patches * 8 chunks, 256 threads. All inputs f32.
// aw2 layout for MFMA conv2: [n][pos 9][oc 128][ic 128] bf16, with ic-slot
// XOR swizzle: slot_stored = (ic>>3) ^ (oc&15), element = slot_stored*8 + (ic&7).
__global__ __launch_bounds__(256) void k_prep(
    const float* __restrict__ v,
    const float* __restrict__ w1, const float* __restrict__ b1,
    const float* __restrict__ w2, const float* __restrict__ b2,
    const float* __restrict__ w3, const float* __restrict__ b3,
    const float* __restrict__ wsca, const float* __restrict__ bsca,
    const float* __restrict__ w4, const float* __restrict__ b4,
    const float* __restrict__ w5, const float* __restrict__ b5,
    float* __restrict__ aw1, float* __restrict__ a4f, float* __restrict__ ascaf,
    float* __restrict__ a3f, float* __restrict__ a5f,
    float* __restrict__ ab1, float* __restrict__ ab2, float* __restrict__ ab4,
    float* __restrict__ abscaf, float* __restrict__ ab3, float* __restrict__ ab5,
    bf16* __restrict__ aw2) {
  int bid = blockIdx.x;
  int n = bid >> 3, sc = bid & 7;
  int b = n / 36, ph = (n % 36) / 6, pw = n % 6;
  float vr[5];
#pragma unroll
  for (int k = 0; k < 5; ++k) vr[k] = v[((b*5 + k)*6 + ph)*6 + pw];
  int t = threadIdx.x;
  for (int j = sc*1024 + t; j < sc*1024 + 1024; j += 256) {
    float s1 = 0.f, s4 = 0.f;
#pragma unroll
    for (int k = 0; k < 5; ++k) {
      s1 += vr[k] * w1[k*8192 + j];
      s4 += vr[k] * w4[k*8192 + j];
    }
    aw1[n*8192 + j] = s1;
    a4f[n*8192 + j] = s4;
  }
  for (int j = sc*512 + t; j < sc*512 + 512; j += 256) {
    float ss = 0.f, s3 = 0.f, s5 = 0.f;
#pragma unroll
    for (int k = 0; k < 5; ++k) {
      ss += vr[k] * wsca[k*4096 + j];
      s3 += vr[k] * w3[k*4096 + j];
      s5 += vr[k] * w5[k*4096 + j];
    }
    ascaf[n*4096 + j] = ss;
    a3f[n*4096 + j] = s3;
    a5f[n*4096 + j] = s5;
  }
  if (sc == 0) {
    if (t < 128) {
      float s1 = 0.f, s2 = 0.f, s4 = 0.f;
#pragma unroll
      for (int k = 0; k < 5; ++k) {
        s1 += vr[k] * b1[k*128 + t];
        s2 += vr[k] * b2[k*128 + t];
        s4 += vr[k] * b4[k*128 + t];
      }
      ab1[n*128 + t] = s1; ab2[n*128 + t] = s2; ab4[n*128 + t] = s4;
    } else if (t < 192) {
      int c = t - 128;
      float ss = 0.f, s3 = 0.f, s5 = 0.f;
#pragma unroll
      for (int k = 0; k < 5; ++k) {
        ss += vr[k] * bsca[k*64 + c];
        s3 += vr[k] * b3[k*64 + c];
        s5 += vr[k] * b5[k*64 + c];
      }
      abscaf[n*64 + c] = ss; ab3[n*64 + c] = s3; ab5[n*64 + c] = s5;
    }
  }
  // aw2: read w2 linear (coalesced): j = ((oc*128 + ic)*3 + kh)*3 + kw
  for (int j = sc*18432 + t; j < sc*18432 + 18432; j += 256) {
    float s = 0.f;
#pragma unroll
    for (int k = 0; k < 5; ++k) s += vr[k] * w2[(size_t)k*147456 + j];
    int oc = j / 1152;
    int rr = j - oc*1152;
    int ic = rr / 9;
    int tt = rr - ic*9;          // pos = kh*3+kw
    int icp = (((ic >> 3) ^ (oc & 15)) << 3) | (ic & 7);
    aw2[(size_t)n*147456 + ((size_t)(tt*128 + oc) << 7) + icp] = __float2bfloat16(s);
  }
}

// ---------------- LN + conv1 (1x1, 64->128) ----------------
// grid = B*H*6 = 4608 blocks, 256 threads. x1 written PIXEL-MAJOR: [b][h][w][128oc]
__global__ __launch_bounds__(256) void k_ln_conv1(
    const float* __restrict__ inp, const float* __restrict__ aw1,
    const float* __restrict__ ab1, const float* __restrict__ n1w,
    const float* __restrict__ n1b, bf16* __restrict__ x1) {
  __shared__ float wl[8192];
  __shared__ float xl[4096];
  __shared__ float bl[128];
  __shared__ float gl[64], bel[64];
  __shared__ float ps[4][64], ps2[4][64];
  int bid = blockIdx.x;
  int b = bid / 2304; int rem = bid % 2304; int h = rem / 6; int pw = rem % 6;
  int ph = h >> 6; int n = (b*6 + ph)*6 + pw; int w0 = pw*64;
  int t = threadIdx.x;
  for (int j = t; j < 8192; j += 256) wl[j] = aw1[n*8192 + j];
  if (t < 128) bl[t] = ab1[n*128 + t];
  if (t < 64) { gl[t] = n1w[t]; bel[t] = n1b[t]; }
  const float* ip = inp + ((size_t)b*64*HH + h)*WW + w0;
  for (int j = t; j < 4096; j += 256) {
    int c = j >> 6, px = j & 63;
    xl[j] = ip[(size_t)c*HWH + px];
  }
  __syncthreads();
  int px = t & 63, part = t >> 6;
  float s = 0.f, s2 = 0.f;
  for (int c = part*16; c < part*16 + 16; ++c) { float xv = xl[c*64 + px]; s += xv; s2 += xv*xv; }
  ps[part][px] = s; ps2[part][px] = s2;
  __syncthreads();
  float mu = (ps[0][px] + ps[1][px] + ps[2][px] + ps[3][px]) * (1.f/64.f);
  float var = (ps2[0][px] + ps2[1][px] + ps2[2][px] + ps2[3][px]) * (1.f/64.f) - mu*mu;
  float rs = rsqrtf(fmaxf(var, 0.f) + EPSV);
  for (int c = part*16; c < part*16 + 16; ++c)
    xl[c*64 + px] = (xl[c*64 + px] - mu) * rs * gl[c] + bel[c];
  __syncthreads();
  float acc[32];
  int ocb = part*32;
#pragma unroll
  for (int o = 0; o < 32; ++o) acc[o] = bl[ocb + o];
  for (int i4 = 0; i4 < 16; ++i4) {
    float x0 = xl[(i4*4+0)*64 + px], x1v = xl[(i4*4+1)*64 + px];
    float x2v = xl[(i4*4+2)*64 + px], x3v = xl[(i4*4+3)*64 + px];
#pragma unroll
    for (int o = 0; o < 32; ++o) {
      const float4 wv = *(const float4*)&wl[(ocb + o)*64 + i4*4];
      acc[o] += wv.x*x0 + wv.y*x1v + wv.z*x2v + wv.w*x3v;
    }
  }
  // pixel-major packed store: 32 consecutive oc = 64B as 4x uint4
  u32t pk[16];
#pragma unroll
  for (int o2 = 0; o2 < 16; ++o2) {
    bf16 lo = __float2bfloat16(acc[2*o2]);
    bf16 hi = __float2bfloat16(acc[2*o2+1]);
    pk[o2] = ((u32t)(*(u16t*)&hi) << 16) | (u32t)(*(u16t*)&lo);
  }
  uint4* xp = (uint4*)(x1 + ((((size_t)b*HH + h)*WW + w0 + px) << 7) + ocb);
#pragma unroll
  for (int q4 = 0; q4 < 4; ++q4)
    xp[q4] = make_uint4(pk[q4*4], pk[q4*4+1], pk[q4*4+2], pk[q4*4+3]);
}

// ---------------- conv2 via MFMA implicit GEMM + SG + pool ----------------
// grid = 72 patches * 32 row-pairs = 2304 blocks, 256 threads (4 waves).
// Block: output rows r0..r0+1 (patch-local), cols 0..63, all 128 oc.
// Wave wv: row rr=wv>>1, cols (wv&1)*32 .. +31. K = 9 pos x 128 ic.
__global__ __launch_bounds__(256) void k_conv2m(
    const bf16* __restrict__ x1, const bf16* __restrict__ aw2,
    const float* __restrict__ ab2, bf16* __restrict__ kx, float* __restrict__ pool) {
  __shared__ alignas(16) u16t xs[4*66*128];     // 67584 B, swizzled ic-slots
  __shared__ alignas(16) u16t wsA[16384];       // 32 KB
  __shared__ alignas(16) u16t wsB[16384];       // 32 KB
  __shared__ float pool_l[64];
  __shared__ float bias_l[128];
  int bid = blockIdx.x;
  int n = bid >> 5, rp = bid & 31;
  int b = n / 36, ph = (n % 36) / 6, pw = n % 6;
  int r0 = rp * 2;
  int t = threadIdx.x;
  if (t < 64) pool_l[t] = 0.f;
  if (t < 128) bias_l[t] = ab2[n*128 + t];

  // stage xs: rows r0-1..r0+2, cols -1..64 (c_l 0..65), zero-padded outside patch
  const bf16* xbase = x1 + ((((size_t)b*HH + ph*64)*WW + pw*64) << 7);
  for (int j = t; j < 4224; j += 256) {
    int s_st = j & 15;
    int rc = j >> 4;
    int c = rc % 66, r = rc / 66;
    int gr = r0 + r - 1, gc = c - 1;
    uint4 val = make_uint4(0u, 0u, 0u, 0u);
    if (gr >= 0 && gr < 64 && gc >= 0 && gc < 64) {
      int s_orig = s_st ^ (c & 15);
      val = *(const uint4*)(xbase + (((size_t)gr*WW + gc) << 7) + s_orig*8);
    }
    *(uint4*)&xs[j*8] = val;
  }
  // stage ws pos 0
  const bf16* wbase = aw2 + (size_t)n*147456;
  for (int j = t; j < 2048; j += 256)
    *(uint4*)&wsA[j*8] = *(const uint4*)(wbase + j*8);
  __syncthreads();

  int wv = t >> 6, l = t & 63;
  int ln = l & 15, lk = l >> 4;
  int rr = wv >> 1;
  int cb0 = (wv & 1) * 32;
  f32x4 acc[8][2];
#pragma unroll
  for (int f = 0; f < 8; ++f)
#pragma unroll
    for (int g = 0; g < 2; ++g) acc[f][g] = (f32x4){0.f, 0.f, 0.f, 0.f};

  uint4 stg[8];
  for (int pos = 0; pos < 9; ++pos) {
    const u16t* wcur = (pos & 1) ? wsB : wsA;
    u16t* wnx = (pos & 1) ? wsA : wsB;
    int dh = pos / 3, dw = pos - dh*3;
    if (pos < 8) {
      const bf16* wp = wbase + (size_t)(pos + 1)*16384;
#pragma unroll
      for (int i = 0; i < 8; ++i) stg[i] = *(const uint4*)(wp + (i*256 + t)*8);
    }
#pragma unroll
    for (int ch = 0; ch < 4; ++ch) {
      short8 af[8];
#pragma unroll
      for (int f = 0; f < 8; ++f) {
        int oc = f*16 + ln;
        int slot = (ch*4 + lk) ^ (oc & 15);
        af[f] = *(const short8*)&wcur[oc*128 + slot*8];
      }
#pragma unroll
      for (int g = 0; g < 2; ++g) {
        int cl = cb0 + g*16 + ln + dw;            // input col + 1
        int row = rr + dh;
        int slot = (ch*4 + lk) ^ (cl & 15);
        short8 bfv = *(const short8*)&xs[(row*66 + cl)*128 + slot*8];
#pragma unroll
        for (int f = 0; f < 8; ++f)
          acc[f][g] = __builtin_amdgcn_mfma_f32_16x16x32_bf16(af[f], bfv, acc[f][g], 0, 0, 0);
      }
    }
    if (pos < 8) {
#pragma unroll
      for (int i = 0; i < 8; ++i) *(uint4*)&wnx[(i*256 + t)*8] = stg[i];
      __syncthreads();
    }
  }

  // epilogue: bias, SimpleGate (q with q+64 -> same lane, frag f vs f+4), store, pool
  int hh = ph*64 + r0 + rr;
  int wcolb = pw*64 + cb0;
  float psum[4][4];
#pragma unroll
  for (int f = 0; f < 4; ++f)
#pragma unroll
    for (int rg = 0; rg < 4; ++rg) psum[f][rg] = 0.f;
#pragma unroll
  for (int f = 0; f < 4; ++f) {
#pragma unroll
    for (int g = 0; g < 2; ++g) {
      f32x4 lo = acc[f][g], hi = acc[f + 4][g];
      int wcol = wcolb + g*16 + ln;
#pragma unroll
      for (int rg = 0; rg < 4; ++rg) {
        int q = f*16 + lk*4 + rg;
        float kv = (lo[rg] + bias_l[q]) * (hi[rg] + bias_l[64 + q]);
        kx[((size_t)(b*64 + q)*HH + hh)*WW + wcol] = __float2bfloat16(kv);
        psum[f][rg] += kv;
      }
    }
  }
#pragma unroll
  for (int f = 0; f < 4; ++f)
#pragma unroll
    for (int rg = 0; rg < 4; ++rg) {
      float s = psum[f][rg];
      s += __shfl_xor(s, 1); s += __shfl_xor(s, 2);
      s += __shfl_xor(s, 4); s += __shfl_xor(s, 8);
      if (ln == 0) atomicAdd(&pool_l[f*16 + lk*4 + rg], s);
    }
  __syncthreads();
  if (t < 64) atomicAdd(&pool[b*64 + t], pool_l[t]);
}

// ---------------- post1: sca conv, pooled-mul, w3 conv, y = inp + x*beta ----------------
__global__ __launch_bounds__(256) void k_post1(
    const bf16* __restrict__ kxg, const float* __restrict__ inp,
    const float* __restrict__ pool,
    const float* __restrict__ ascaf, const float* __restrict__ abscaf,
    const float* __restrict__ a3f, const float* __restrict__ ab3,
    const float* __restrict__ beta, float* __restrict__ yws) {
  __shared__ float wA[4096];
  __shared__ float wB[4096];
  __shared__ float bufA[4096];
  __shared__ float bufB[4096];
  __shared__ float bsl[64], b3l[64], pol[64], betal[64];
  int bid = blockIdx.x;
  int b = bid / 2304; int rem = bid % 2304; int h = rem / 6; int pw = rem % 6;
  int ph = h >> 6; int n = (b*6 + ph)*6 + pw; int w0 = pw*64;
  int t = threadIdx.x;
  for (int j = t; j < 4096; j += 256) { wA[j] = ascaf[n*4096 + j]; wB[j] = a3f[n*4096 + j]; }
  if (t < 64) {
    bsl[t] = abscaf[n*64 + t];
    b3l[t] = ab3[n*64 + t];
    pol[t] = pool[b*64 + t] * (1.0f/147456.0f);
    betal[t] = beta[t];
  }
  const bf16* kxp = kxg + ((size_t)b*64*HH + h)*WW + w0;
  for (int j = t; j < 4096; j += 256) {
    int c = j >> 6, px = j & 63;
    bufA[j] = __bfloat162float(kxp[(size_t)c*HWH + px]);
  }
  __syncthreads();
  int px = t & 63, part = t >> 6;
  int ob = part*16;
  float acc[16];
#pragma unroll
  for (int o = 0; o < 16; ++o) acc[o] = bsl[ob + o];
  for (int i4 = 0; i4 < 16; ++i4) {
    float x0 = bufA[(i4*4+0)*64 + px], x1v = bufA[(i4*4+1)*64 + px];
    float x2v = bufA[(i4*4+2)*64 + px], x3v = bufA[(i4*4+3)*64 + px];
#pragma unroll
    for (int o = 0; o < 16; ++o) {
      const float4 wv = *(const float4*)&wA[(ob + o)*64 + i4*4];
      acc[o] += wv.x*x0 + wv.y*x1v + wv.z*x2v + wv.w*x3v;
    }
  }
#pragma unroll
  for (int o = 0; o < 16; ++o) bufB[(ob + o)*64 + px] = pol[ob + o] * acc[o];
  __syncthreads();
#pragma unroll
  for (int o = 0; o < 16; ++o) acc[o] = b3l[ob + o];
  for (int i4 = 0; i4 < 16; ++i4) {
    float x0 = bufB[(i4*4+0)*64 + px], x1v = bufB[(i4*4+1)*64 + px];
    float x2v = bufB[(i4*4+2)*64 + px], x3v = bufB[(i4*4+3)*64 + px];
#pragma unroll
    for (int o = 0; o < 16; ++o) {
      const float4 wv = *(const float4*)&wB[(ob + o)*64 + i4*4];
      acc[o] += wv.x*x0 + wv.y*x1v + wv.z*x2v + wv.w*x3v;
    }
  }
  const float* inpp = inp + ((size_t)b*64*HH + h)*WW + w0;
  float* yp = yws + ((size_t)b*64*HH + h)*WW + w0;
#pragma unroll
  for (int o = 0; o < 16; ++o) {
    int c = ob + o;
    yp[(size_t)c*HWH + px] = inpp[(size_t)c*HWH + px] + acc[o]*betal[c];
  }
}

// ---------------- post2: LN(y), w4, SG, w5, out = y + x*gamma ----------------
__global__ __launch_bounds__(256) void k_post2(
    const float* __restrict__ yws,
    const float* __restrict__ a4f, const float* __restrict__ ab4,
    const float* __restrict__ a5f, const float* __restrict__ ab5,
    const float* __restrict__ n2w, const float* __restrict__ n2b,
    const float* __restrict__ gamma, float* __restrict__ outp) {
  __shared__ float w4l[8192];
  __shared__ alignas(16) u16t w5l[4096];
  __shared__ float yb[4096];
  __shared__ float lnb[4096];
  __shared__ float ps[4][64], ps2[4][64];
  __shared__ float b4l[128], b5l[64], gl[64], bel[64], gml[64];
  int bid = blockIdx.x;
  int b = bid / 2304; int rem = bid % 2304; int h = rem / 6; int pw = rem % 6;
  int ph = h >> 6; int n = (b*6 + ph)*6 + pw; int w0 = pw*64;
  int t = threadIdx.x;
  for (int j = t; j < 8192; j += 256) w4l[j] = a4f[n*8192 + j];
  for (int j = t; j < 4096; j += 256) {
    bf16 hbits = __float2bfloat16(a5f[n*4096 + j]);
    w5l[j] = *reinterpret_cast<u16t*>(&hbits);
  }
  if (t < 128) b4l[t] = ab4[n*128 + t];
  if (t < 64) {
    b5l[t] = ab5[n*64 + t];
    gl[t]  = n2w[t];
    bel[t] = n2b[t];
    gml[t] = gamma[t];
  }
  const float* yp = yws + ((size_t)b*64*HH + h)*WW + w0;
  for (int j = t; j < 4096; j += 256) {
    int c = j >> 6, px = j & 63;
    yb[j] = yp[(size_t)c*HWH + px];
  }
  __syncthreads();
  int px = t & 63, part = t >> 6;
  float s = 0.f, s2 = 0.f;
  for (int c = part*16; c < part*16 + 16; ++c) { float yv = yb[c*64 + px]; s += yv; s2 += yv*yv; }
  ps[part][px] = s; ps2[part][px] = s2;
  __syncthreads();
  float mu = (ps[0][px] + ps[1][px] + ps[2][px] + ps[3][px]) * (1.f/64.f);
  float var = (ps2[0][px] + ps2[1][px] + ps2[2][px] + ps2[3][px]) * (1.f/64.f) - mu*mu;
  float rs = rsqrtf(fmaxf(var, 0.f) + EPSV);
  for (int c = part*16; c < part*16 + 16; ++c)
    lnb[c*64 + px] = (yb[c*64 + px] - mu) * rs * gl[c] + bel[c];
  __syncthreads();
  int qb = part*16;
  float sL[16], sH[16];
#pragma unroll
  for (int q = 0; q < 16; ++q) { sL[q] = b4l[qb + q]; sH[q] = b4l[64 + qb + q]; }
  for (int i4 = 0; i4 < 16; ++i4) {
    float x0 = lnb[(i4*4+0)*64 + px], x1v = lnb[(i4*4+1)*64 + px];
    float x2v = lnb[(i4*4+2)*64 + px], x3v = lnb[(i4*4+3)*64 + px];
#pragma unroll
    for (int q = 0; q < 16; ++q) {
      const float4 wL = *(const float4*)&w4l[(qb + q)*64 + i4*4];
      sL[q] += wL.x*x0 + wL.y*x1v + wL.z*x2v + wL.w*x3v;
      const float4 wH = *(const float4*)&w4l[(64 + qb + q)*64 + i4*4];
      sH[q] += wH.x*x0 + wH.y*x1v + wH.z*x2v + wH.w*x3v;
    }
  }
  __syncthreads();
#pragma unroll
  for (int q = 0; q < 16; ++q) lnb[(qb + q)*64 + px] = sL[q]*sH[q];
  __syncthreads();
  int ob = qb;
  float acc[16];
#pragma unroll
  for (int o = 0; o < 16; ++o) acc[o] = b5l[ob + o];
  for (int i4 = 0; i4 < 16; ++i4) {
    float x0 = lnb[(i4*4+0)*64 + px], x1v = lnb[(i4*4+1)*64 + px];
    float x2v = lnb[(i4*4+2)*64 + px], x3v = lnb[(i4*4+3)*64 + px];
#pragma unroll
    for (int o = 0; o < 16; ++o) {
      uint2 wp = *(const uint2*)&w5l[(ob + o)*64 + i4*4];
      acc[o] += bflo(wp.x)*x0 + bfhi(wp.x)*x1v + bflo(wp.y)*x2v + bfhi(wp.y)*x3v;
    }
  }
  float* op = outp + ((size_t)b*64*HH + h)*WW + w0;
#pragma unroll
  for (int o = 0; o < 16; ++o) {
    int c = ob + o;
    op[(size_t)c*HWH + px] = yb[c*64 + px] + acc[o]*gml[c];
  }
}

extern "C" void kernel_launch(void* const* d_in, const int* in_sizes, int n_in,
                              void* d_out, int out_size, void* d_ws, size_t ws_size,
                              hipStream_t stream) {
  (void)in_sizes; (void)n_in; (void)out_size; (void)ws_size;
  const float* inp  = (const float*)d_in[0];
  const float* v    = (const float*)d_in[1];
  const float* w1   = (const float*)d_in[2];
  const float* b1   = (const float*)d_in[3];
  const float* w2   = (const float*)d_in[4];
  const float* b2   = (const float*)d_in[5];
  const float* w3   = (const float*)d_in[6];
  const float* b3   = (const float*)d_in[7];
  const float* wsca = (const float*)d_in[8];
  const float* bsca = (const float*)d_in[9];
  const float* w4   = (const float*)d_in[10];
  const float* b4   = (const float*)d_in[11];
  const float* w5   = (const float*)d_in[12];
  const float* b5   = (const float*)d_in[13];
  const float* n1w  = (const float*)d_in[14];
  const float* n1b  = (const float*)d_in[15];
  const float* n2w  = (const float*)d_in[16];
  const float* n2b  = (const float*)d_in[17];
  const float* beta = (const float*)d_in[18];
  const float* gamma= (const float*)d_in[19];

  float* wsf  = (float*)d_ws;
  float* pool = wsf;                    // [2][64]
  float* aw1  = wsf + 128;              // [72][128][64]
  float* a4f  = aw1 + 589824;           // [72][128][64]
  float* ascaf= a4f + 589824;           // [72][64][64]
  float* a3f  = ascaf + 294912;         // [72][64][64]
  float* a5f  = a3f + 294912;           // [72][64][64]
  float* ab1  = a5f + 294912;           // [72][128]
  float* ab2  = ab1 + 9216;
  float* ab4  = ab2 + 9216;
  float* abscaf = ab4 + 9216;           // [72][64]
  float* ab3  = abscaf + 4608;
  float* ab5  = ab3 + 4608;
  bf16* aw2   = (bf16*)(ab5 + 4608);    // [72][9][128][128] bf16 (swizzled)
  bf16* x1    = aw2 + 10616832;         // [2][384][384][128] bf16 pixel-major
  bf16* kxb   = x1 + 37748736;          // keep_x bf16 [2][64][384][384]
  float* out0 = (float*)d_out;
  float* yws  = out0;                   // y aliases d_out

  hipMemsetAsync(pool, 0, 128*sizeof(float), stream);
  k_prep<<<dim3(576), dim3(256), 0, stream>>>(v, w1, b1, w2, b2, w3, b3, wsca, bsca,
      w4, b4, w5, b5, aw1, a4f, ascaf, a3f, a5f, ab1, ab2, ab4, abscaf, ab3, ab5, aw2);
  k_ln_conv1<<<dim3(4608), dim3(256), 0, stream>>>(inp, aw1, ab1, n1w, n1b, x1);
  k_conv2m<<<dim3(2304), dim3(256), 0, stream>>>(x1, aw2, ab2, kxb, pool);
  k_post1<<<dim3(4608), dim3(256), 0, stream>>>(kxb, inp, pool, ascaf, abscaf, a3f, ab3, beta, yws);
  k_post2<<<dim3(4608), dim3(256), 0, stream>>>(yws, a4f, ab4, a5f, ab5, n2w, n2b, gamma, out0);
  hipMemcpyAsync((char*)d_out + (size_t)18874368*4, d_in[1], 360*4,
                 hipMemcpyDeviceToDevice, stream);
}

// Round 5
// 532.183 us; speedup vs baseline: 6.7164x; 1.5987x over previous
//
#include <hip/hip_runtime.h>
#include <hip/hip_bf16.h>

typedef __hip_bfloat16 bf16;
typedef unsigned short u16t;
typedef unsigned int u32t;
typedef __attribute__((ext_vector_type(8))) short short8;
typedef __attribute__((ext_vector_type(4))) float f32x4;

#define HH 384
#define WW 384
#define HWH 147456
#define EPSV 1e-6f

__device__ __forceinline__ u32t pk2(float a, float b) {
  bf16 lo = __float2bfloat16(a), hi = __float2bfloat16(b);
  return ((u32t)(*(u16t*)&hi) << 16) | (u32t)(*(u16t*)&lo);
}

// ---------------- prep: per-patch aggregated weights ----------------
// All 1x1 weights emitted bf16 PRE-SWIZZLED: [oc][64ic], elem stored at
// oc*64 + ((ic>>3)^(oc&7))*8 + (ic&7)   (128B rows, bank-balanced b128 reads)
__global__ __launch_bounds__(256) void k_prep(
    const float* __restrict__ v,
    const float* __restrict__ w1, const float* __restrict__ b1,
    const float* __restrict__ w2, const float* __restrict__ b2,
    const float* __restrict__ w3, const float* __restrict__ b3,
    const float* __restrict__ wsca, const float* __restrict__ bsca,
    const float* __restrict__ w4, const float* __restrict__ b4,
    const float* __restrict__ w5, const float* __restrict__ b5,
    bf16* __restrict__ aw1b, bf16* __restrict__ a4b, bf16* __restrict__ ascab,
    bf16* __restrict__ a3b, bf16* __restrict__ a5b,
    float* __restrict__ ab1, float* __restrict__ ab2, float* __restrict__ ab4,
    float* __restrict__ abscaf, float* __restrict__ ab3, float* __restrict__ ab5,
    bf16* __restrict__ aw2) {
  int bid = blockIdx.x;
  int n = bid >> 3, sc = bid & 7;
  int b = n / 36, ph = (n % 36) / 6, pw = n % 6;
  float vr[5];
#pragma unroll
  for (int k = 0; k < 5; ++k) vr[k] = v[((b*5 + k)*6 + ph)*6 + pw];
  int t = threadIdx.x;
  // aw1b / a4b: [128][64]
  for (int j = sc*1024 + t; j < sc*1024 + 1024; j += 256) {
    float s1 = 0.f, s4 = 0.f;
#pragma unroll
    for (int k = 0; k < 5; ++k) {
      s1 += vr[k] * w1[k*8192 + j];
      s4 += vr[k] * w4[k*8192 + j];
    }
    int oc = j >> 6, ic = j & 63;
    int idx = n*8192 + oc*64 + (((ic >> 3) ^ (oc & 7)) << 3) + (ic & 7);
    aw1b[idx] = __float2bfloat16(s1);
    a4b[idx]  = __float2bfloat16(s4);
  }
  // ascab / a3b / a5b: [64][64]
  for (int j = sc*512 + t; j < sc*512 + 512; j += 256) {
    float ss = 0.f, s3 = 0.f, s5 = 0.f;
#pragma unroll
    for (int k = 0; k < 5; ++k) {
      ss += vr[k] * wsca[k*4096 + j];
      s3 += vr[k] * w3[k*4096 + j];
      s5 += vr[k] * w5[k*4096 + j];
    }
    int oc = j >> 6, ic = j & 63;
    int idx = n*4096 + oc*64 + (((ic >> 3) ^ (oc & 7)) << 3) + (ic & 7);
    ascab[idx] = __float2bfloat16(ss);
    a3b[idx]   = __float2bfloat16(s3);
    a5b[idx]   = __float2bfloat16(s5);
  }
  if (sc == 0) {
    if (t < 128) {
      float s1 = 0.f, s2 = 0.f, s4 = 0.f;
#pragma unroll
      for (int k = 0; k < 5; ++k) {
        s1 += vr[k] * b1[k*128 + t];
        s2 += vr[k] * b2[k*128 + t];
        s4 += vr[k] * b4[k*128 + t];
      }
      ab1[n*128 + t] = s1; ab2[n*128 + t] = s2; ab4[n*128 + t] = s4;
    } else if (t < 192) {
      int c = t - 128;
      float ss = 0.f, s3 = 0.f, s5 = 0.f;
#pragma unroll
      for (int k = 0; k < 5; ++k) {
        ss += vr[k] * bsca[k*64 + c];
        s3 += vr[k] * b3[k*64 + c];
        s5 += vr[k] * b5[k*64 + c];
      }
      abscaf[n*64 + c] = ss; ab3[n*64 + c] = s3; ab5[n*64 + c] = s5;
    }
  }
  // aw2 (3x3): [n][pos 9][oc 128][ic 128] bf16, slot16 ^ (oc&15) swizzle
  for (int j = sc*18432 + t; j < sc*18432 + 18432; j += 256) {
    float s = 0.f;
#pragma unroll
    for (int k = 0; k < 5; ++k) s += vr[k] * w2[(size_t)k*147456 + j];
    int oc = j / 1152;
    int rr = j - oc*1152;
    int ic = rr / 9;
    int tt = rr - ic*9;
    int icp = (((ic >> 3) ^ (oc & 15)) << 3) | (ic & 7);
    aw2[(size_t)n*147456 + ((size_t)(tt*128 + oc) << 7) + icp] = __float2bfloat16(s);
  }
}

// ---------------- LN + conv1 (MFMA 1x1, 64->128) ----------------
// grid 4608, 256 threads. x1 pixel-major [b][h][w][128].
__global__ __launch_bounds__(256) void k_ln_conv1(
    const float* __restrict__ inp, const bf16* __restrict__ aw1b,
    const float* __restrict__ ab1, const float* __restrict__ n1w,
    const float* __restrict__ n1b, bf16* __restrict__ x1) {
  __shared__ alignas(16) float xl[4096];          // input tile; reused as bf16 stage
  __shared__ alignas(16) u16t wA[8192];           // [128][64] swz
  __shared__ alignas(16) u16t lnb[4096];          // [64px][64ic] swz
  __shared__ float bl[128];
  __shared__ float gl[64], bel[64];
  __shared__ float ps[4][64], ps2[4][64];
  int bid = blockIdx.x;
  int b = bid / 2304; int rem = bid % 2304; int h = rem / 6; int pw = rem % 6;
  int ph = h >> 6; int n = (b*6 + ph)*6 + pw; int w0 = pw*64;
  int t = threadIdx.x;
  for (int j = t; j < 1024; j += 256)
    ((uint4*)wA)[j] = ((const uint4*)(aw1b + (size_t)n*8192))[j];
  if (t < 128) bl[t] = ab1[n*128 + t];
  if (t < 64) { gl[t] = n1w[t]; bel[t] = n1b[t]; }
  const float* ip = inp + ((size_t)b*64*HH + h)*WW + w0;
  for (int j = t; j < 4096; j += 256) {
    int c = j >> 6, px = j & 63;
    xl[j] = ip[(size_t)c*HWH + px];
  }
  __syncthreads();
  int px = t & 63, part = t >> 6;
  {
    float s = 0.f, s2 = 0.f;
    for (int c = part*16; c < part*16 + 16; ++c) { float xv = xl[c*64 + px]; s += xv; s2 += xv*xv; }
    ps[part][px] = s; ps2[part][px] = s2;
  }
  __syncthreads();
  float mu = (ps[0][px] + ps[1][px] + ps[2][px] + ps[3][px]) * (1.f/64.f);
  float var = (ps2[0][px] + ps2[1][px] + ps2[2][px] + ps2[3][px]) * (1.f/64.f) - mu*mu;
  float rs = rsqrtf(fmaxf(var, 0.f) + EPSV);
  {
    float lv[16];
#pragma unroll
    for (int cc = 0; cc < 16; ++cc) {
      int c = part*16 + cc;
      lv[cc] = (xl[c*64 + px] - mu) * rs * gl[c] + bel[c];
    }
    *(uint4*)&lnb[px*64 + (((part*2) ^ (px&7)) << 3)] =
        make_uint4(pk2(lv[0],lv[1]), pk2(lv[2],lv[3]), pk2(lv[4],lv[5]), pk2(lv[6],lv[7]));
    *(uint4*)&lnb[px*64 + (((part*2+1) ^ (px&7)) << 3)] =
        make_uint4(pk2(lv[8],lv[9]), pk2(lv[10],lv[11]), pk2(lv[12],lv[13]), pk2(lv[14],lv[15]));
  }
  __syncthreads();
  int wv = t >> 6, l = t & 63, ln = l & 15, lk = l >> 4;
  f32x4 acc[2][4];
#pragma unroll
  for (int i = 0; i < 2; ++i)
#pragma unroll
    for (int g = 0; g < 4; ++g)
#pragma unroll
      for (int rg = 0; rg < 4; ++rg)
        acc[i][g][rg] = bl[(2*wv + i)*16 + lk*4 + rg];
#pragma unroll
  for (int ch = 0; ch < 2; ++ch) {
    int slx = ((ch*4 + lk) ^ (ln & 7)) << 3;
    short8 a0 = *(const short8*)&wA[((2*wv + 0)*16 + ln)*64 + slx];
    short8 a1 = *(const short8*)&wA[((2*wv + 1)*16 + ln)*64 + slx];
#pragma unroll
    for (int g = 0; g < 4; ++g) {
      short8 bv = *(const short8*)&lnb[(g*16 + ln)*64 + slx];
      acc[0][g] = __builtin_amdgcn_mfma_f32_16x16x32_bf16(a0, bv, acc[0][g], 0, 0, 0);
      acc[1][g] = __builtin_amdgcn_mfma_f32_16x16x32_bf16(a1, bv, acc[1][g], 0, 0, 0);
    }
  }
  // D -> LDS stage (swizzled 8B granules), then coalesced copy-out
  u16t* stg = (u16t*)xl;   // 64px x 128oc bf16 = 16KB
#pragma unroll
  for (int i = 0; i < 2; ++i)
#pragma unroll
    for (int g = 0; g < 4; ++g) {
      int pxd = g*16 + ln;
      int g8 = (2*wv + i)*4 + lk;             // oc>>2
      int st = g8 ^ (pxd & 15);
      *(uint2*)&stg[pxd*128 + (st << 2)] =
          make_uint2(pk2(acc[i][g][0], acc[i][g][1]), pk2(acc[i][g][2], acc[i][g][3]));
    }
  __syncthreads();
  bf16* xp = x1 + (((size_t)b*HH + h)*WW + w0)*128;
  for (int j = t; j < 2048; j += 256) {
    int pxd = j >> 5, gs = j & 31;
    uint2 val = *(uint2*)&stg[pxd*128 + (gs << 2)];
    *(uint2*)(xp + (size_t)pxd*128 + ((gs ^ (pxd & 15)) << 2)) = val;
  }
}

// ---------------- conv2 via MFMA implicit GEMM + SG + pool ----------------
// grid = 2304 blocks, 256 threads. kx now PIXEL-MAJOR [b][h][w][64].
__global__ __launch_bounds__(256) void k_conv2m(
    const bf16* __restrict__ x1, const bf16* __restrict__ aw2,
    const float* __restrict__ ab2, bf16* __restrict__ kx, float* __restrict__ pool) {
  __shared__ alignas(16) u16t xs[4*66*128];     // 67584 B; reused as kx stage
  __shared__ alignas(16) u16t wsA[16384];
  __shared__ alignas(16) u16t wsB[16384];
  __shared__ float pool_l[64];
  __shared__ float bias_l[128];
  int bid = blockIdx.x;
  int n = bid >> 5, rp = bid & 31;
  int b = n / 36, ph = (n % 36) / 6, pw = n % 6;
  int r0 = rp * 2;
  int t = threadIdx.x;
  if (t < 64) pool_l[t] = 0.f;
  if (t < 128) bias_l[t] = ab2[n*128 + t];

  const bf16* xbase = x1 + ((((size_t)b*HH + ph*64)*WW + pw*64) << 7);
  for (int j = t; j < 4224; j += 256) {
    int s_st = j & 15;
    int rc = j >> 4;
    int c = rc % 66, r = rc / 66;
    int gr = r0 + r - 1, gc = c - 1;
    uint4 val = make_uint4(0u, 0u, 0u, 0u);
    if (gr >= 0 && gr < 64 && gc >= 0 && gc < 64) {
      int s_orig = s_st ^ (c & 15);
      val = *(const uint4*)(xbase + (((size_t)gr*WW + gc) << 7) + s_orig*8);
    }
    *(uint4*)&xs[j*8] = val;
  }
  const bf16* wbase = aw2 + (size_t)n*147456;
  for (int j = t; j < 2048; j += 256)
    *(uint4*)&wsA[j*8] = *(const uint4*)(wbase + j*8);
  __syncthreads();

  int wv = t >> 6, l = t & 63;
  int ln = l & 15, lk = l >> 4;
  int rr = wv >> 1;
  int cb0 = (wv & 1) * 32;
  f32x4 acc[8][2];
#pragma unroll
  for (int f = 0; f < 8; ++f)
#pragma unroll
    for (int g = 0; g < 2; ++g) acc[f][g] = (f32x4){0.f, 0.f, 0.f, 0.f};

  uint4 stgld[8];
  for (int pos = 0; pos < 9; ++pos) {
    const u16t* wcur = (pos & 1) ? wsB : wsA;
    u16t* wnx = (pos & 1) ? wsA : wsB;
    int dh = pos / 3, dw = pos - dh*3;
    if (pos < 8) {
      const bf16* wp = wbase + (size_t)(pos + 1)*16384;
#pragma unroll
      for (int i = 0; i < 8; ++i) stgld[i] = *(const uint4*)(wp + (i*256 + t)*8);
    }
#pragma unroll
    for (int ch = 0; ch < 4; ++ch) {
      short8 af[8];
#pragma unroll
      for (int f = 0; f < 8; ++f) {
        int oc = f*16 + ln;
        int slot = (ch*4 + lk) ^ (oc & 15);
        af[f] = *(const short8*)&wcur[oc*128 + slot*8];
      }
#pragma unroll
      for (int g = 0; g < 2; ++g) {
        int cl = cb0 + g*16 + ln + dw;
        int row = rr + dh;
        int slot = (ch*4 + lk) ^ (cl & 15);
        short8 bfv = *(const short8*)&xs[(row*66 + cl)*128 + slot*8];
#pragma unroll
        for (int f = 0; f < 8; ++f)
          acc[f][g] = __builtin_amdgcn_mfma_f32_16x16x32_bf16(af[f], bfv, acc[f][g], 0, 0, 0);
      }
    }
    if (pos < 8) {
#pragma unroll
      for (int i = 0; i < 8; ++i) *(uint4*)&wnx[(i*256 + t)*8] = stgld[i];
      __syncthreads();
    }
  }

  __syncthreads();                 // all xs reads done -> reuse xs as stage
  u16t* stg = xs;                  // [2 rows][64 cols][64 q] bf16 = 16KB
  float psum[4][4];
#pragma unroll
  for (int f = 0; f < 4; ++f)
#pragma unroll
    for (int rg = 0; rg < 4; ++rg) psum[f][rg] = 0.f;
#pragma unroll
  for (int f = 0; f < 4; ++f) {
#pragma unroll
    for (int g = 0; g < 2; ++g) {
      f32x4 lo = acc[f][g], hi = acc[f + 4][g];
      int col = cb0 + g*16 + ln;
      float kv[4];
#pragma unroll
      for (int rg = 0; rg < 4; ++rg) {
        int q = f*16 + lk*4 + rg;
        kv[rg] = (lo[rg] + bias_l[q]) * (hi[rg] + bias_l[64 + q]);
        psum[f][rg] += kv[rg];
      }
      int gq = f*4 + lk;
      int st = gq ^ (col & 15);
      *(uint2*)&stg[rr*4096 + col*64 + (st << 2)] =
          make_uint2(pk2(kv[0], kv[1]), pk2(kv[2], kv[3]));
    }
  }
#pragma unroll
  for (int f = 0; f < 4; ++f)
#pragma unroll
    for (int rg = 0; rg < 4; ++rg) {
      float s = psum[f][rg];
      s += __shfl_xor(s, 1); s += __shfl_xor(s, 2);
      s += __shfl_xor(s, 4); s += __shfl_xor(s, 8);
      if (ln == 0) atomicAdd(&pool_l[f*16 + lk*4 + rg], s);
    }
  __syncthreads();
  for (int j = t; j < 2048; j += 256) {
    int rr2 = j >> 10, remj = j & 1023, col = remj >> 4, gs = remj & 15;
    uint2 val = *(uint2*)&stg[rr2*4096 + col*64 + (gs << 2)];
    int hh2 = ph*64 + r0 + rr2;
    int gcol = pw*64 + col;
    *(uint2*)(kx + ((((size_t)b*HH + hh2)*WW + gcol) << 6) + ((gs ^ (col & 15)) << 2)) = val;
  }
  if (t < 64) atomicAdd(&pool[b*64 + t], pool_l[t]);
}

// ---------------- post1 (MFMA): sca conv, pooled-mul, w3 conv, y = inp + x*beta ----------------
__global__ __launch_bounds__(256) void k_post1(
    const bf16* __restrict__ kxg, const float* __restrict__ inp,
    const float* __restrict__ pool,
    const bf16* __restrict__ ascab, const float* __restrict__ abscaf,
    const bf16* __restrict__ a3b, const float* __restrict__ ab3,
    const float* __restrict__ beta, float* __restrict__ yws) {
  __shared__ alignas(16) u16t wS[4096];
  __shared__ alignas(16) u16t w3S[4096];
  __shared__ alignas(16) u16t B1[4096];
  __shared__ alignas(16) u16t B2[4096];
  __shared__ float bsl[64], b3l[64], pol[64], betal[64];
  int bid = blockIdx.x;
  int b = bid / 2304; int rem = bid % 2304; int h = rem / 6; int pw = rem % 6;
  int ph = h >> 6; int n = (b*6 + ph)*6 + pw; int w0 = pw*64;
  int t = threadIdx.x;
  for (int j = t; j < 512; j += 256) {
    ((uint4*)wS)[j]  = ((const uint4*)(ascab + (size_t)n*4096))[j];
    ((uint4*)w3S)[j] = ((const uint4*)(a3b + (size_t)n*4096))[j];
  }
  if (t < 64) {
    bsl[t] = abscaf[n*64 + t];
    b3l[t] = ab3[n*64 + t];
    pol[t] = pool[b*64 + t] * (1.0f/147456.0f);
    betal[t] = beta[t];
  }
  const bf16* kxp = kxg + (((size_t)b*HH + h)*WW + w0)*64;
  for (int j = t; j < 512; j += 256) {
    int px = j >> 3, sl = j & 7;
    *(uint4*)&B1[px*64 + ((sl ^ (px & 7)) << 3)] = *(const uint4*)(kxp + px*64 + sl*8);
  }
  __syncthreads();
  int wv = t >> 6, l = t & 63, ln = l & 15, lk = l >> 4;
  // GEMM1: sca
  f32x4 acc[4];
#pragma unroll
  for (int g = 0; g < 4; ++g)
#pragma unroll
    for (int rg = 0; rg < 4; ++rg) acc[g][rg] = bsl[wv*16 + lk*4 + rg];
#pragma unroll
  for (int ch = 0; ch < 2; ++ch) {
    int slx = ((ch*4 + lk) ^ (ln & 7)) << 3;
    short8 a = *(const short8*)&wS[(wv*16 + ln)*64 + slx];
#pragma unroll
    for (int g = 0; g < 4; ++g) {
      short8 bv = *(const short8*)&B1[(g*16 + ln)*64 + slx];
      acc[g] = __builtin_amdgcn_mfma_f32_16x16x32_bf16(a, bv, acc[g], 0, 0, 0);
    }
  }
  // scale by pooled mean, write B2 (swizzled)
#pragma unroll
  for (int g = 0; g < 4; ++g) {
    int px = g*16 + ln;
    float v[4];
#pragma unroll
    for (int rg = 0; rg < 4; ++rg) v[rg] = acc[g][rg] * pol[wv*16 + lk*4 + rg];
    int base = px*64 + (((2*wv + (lk >> 1)) ^ (px & 7)) << 3) + (lk & 1)*4;
    *(uint2*)&B2[base] = make_uint2(pk2(v[0], v[1]), pk2(v[2], v[3]));
  }
  __syncthreads();
  // GEMM2: w3
  f32x4 acc2[4];
#pragma unroll
  for (int g = 0; g < 4; ++g)
#pragma unroll
    for (int rg = 0; rg < 4; ++rg) acc2[g][rg] = b3l[wv*16 + lk*4 + rg];
#pragma unroll
  for (int ch = 0; ch < 2; ++ch) {
    int slx = ((ch*4 + lk) ^ (ln & 7)) << 3;
    short8 a = *(const short8*)&w3S[(wv*16 + ln)*64 + slx];
#pragma unroll
    for (int g = 0; g < 4; ++g) {
      short8 bv = *(const short8*)&B2[(g*16 + ln)*64 + slx];
      acc2[g] = __builtin_amdgcn_mfma_f32_16x16x32_bf16(a, bv, acc2[g], 0, 0, 0);
    }
  }
  const float* inpp = inp + ((size_t)b*64*HH + h)*WW + w0;
  float* yp = yws + ((size_t)b*64*HH + h)*WW + w0;
#pragma unroll
  for (int g = 0; g < 4; ++g) {
    int px = g*16 + ln;
#pragma unroll
    for (int rg = 0; rg < 4; ++rg) {
      int oc = wv*16 + lk*4 + rg;
      yp[(size_t)oc*HWH + px] = inpp[(size_t)oc*HWH + px] + acc2[g][rg]*betal[oc];
    }
  }
}

// ---------------- post2 (MFMA): LN(y), w4, SG, w5, out = y + x*gamma ----------------
__global__ __launch_bounds__(256) void k_post2(
    const float* __restrict__ yws,
    const bf16* __restrict__ a4b, const float* __restrict__ ab4,
    const bf16* __restrict__ a5b, const float* __restrict__ ab5,
    const float* __restrict__ n2w, const float* __restrict__ n2b,
    const float* __restrict__ gamma, float* __restrict__ outp) {
  __shared__ alignas(16) float yb[4096];
  __shared__ alignas(16) u16t w4S[8192];
  __shared__ alignas(16) u16t w5S[4096];
  __shared__ alignas(16) u16t pxb[4096];   // LN out, then SG out
  __shared__ float ps[4][64], ps2[4][64];
  __shared__ float b4l[128], b5l[64], gl[64], bel[64], gml[64];
  int bid = blockIdx.x;
  int b = bid / 2304; int rem = bid % 2304; int h = rem / 6; int pw = rem % 6;
  int ph = h >> 6; int n = (b*6 + ph)*6 + pw; int w0 = pw*64;
  int t = threadIdx.x;
  for (int j = t; j < 1024; j += 256)
    ((uint4*)w4S)[j] = ((const uint4*)(a4b + (size_t)n*8192))[j];
  for (int j = t; j < 512; j += 256)
    ((uint4*)w5S)[j] = ((const uint4*)(a5b + (size_t)n*4096))[j];
  if (t < 128) b4l[t] = ab4[n*128 + t];
  if (t < 64) {
    b5l[t] = ab5[n*64 + t];
    gl[t]  = n2w[t];
    bel[t] = n2b[t];
    gml[t] = gamma[t];
  }
  const float* yp = yws + ((size_t)b*64*HH + h)*WW + w0;
  for (int j = t; j < 4096; j += 256) {
    int c = j >> 6, px = j & 63;
    yb[j] = yp[(size_t)c*HWH + px];
  }
  __syncthreads();
  int px = t & 63, part = t >> 6;
  {
    float s = 0.f, s2 = 0.f;
    for (int c = part*16; c < part*16 + 16; ++c) { float yv = yb[c*64 + px]; s += yv; s2 += yv*yv; }
    ps[part][px] = s; ps2[part][px] = s2;
  }
  __syncthreads();
  float mu = (ps[0][px] + ps[1][px] + ps[2][px] + ps[3][px]) * (1.f/64.f);
  float var = (ps2[0][px] + ps2[1][px] + ps2[2][px] + ps2[3][px]) * (1.f/64.f) - mu*mu;
  float rs = rsqrtf(fmaxf(var, 0.f) + EPSV);
  {
    float lv[16];
#pragma unroll
    for (int cc = 0; cc < 16; ++cc) {
      int c = part*16 + cc;
      lv[cc] = (yb[c*64 + px] - mu) * rs * gl[c] + bel[c];
    }
    *(uint4*)&pxb[px*64 + (((part*2) ^ (px&7)) << 3)] =
        make_uint4(pk2(lv[0],lv[1]), pk2(lv[2],lv[3]), pk2(lv[4],lv[5]), pk2(lv[6],lv[7]));
    *(uint4*)&pxb[px*64 + (((part*2+1) ^ (px&7)) << 3)] =
        make_uint4(pk2(lv[8],lv[9]), pk2(lv[10],lv[11]), pk2(lv[12],lv[13]), pk2(lv[14],lv[15]));
  }
  __syncthreads();
  int wv = t >> 6, l = t & 63, ln = l & 15, lk = l >> 4;
  // w4 GEMM: wave wv owns oc-frags {wv, wv+4} so SG pairs share a lane
  f32x4 accL[4], accH[4];
#pragma unroll
  for (int g = 0; g < 4; ++g)
#pragma unroll
    for (int rg = 0; rg < 4; ++rg) {
      accL[g][rg] = b4l[wv*16 + lk*4 + rg];
      accH[g][rg] = b4l[64 + wv*16 + lk*4 + rg];
    }
#pragma unroll
  for (int ch = 0; ch < 2; ++ch) {
    int slx = ((ch*4 + lk) ^ (ln & 7)) << 3;
    short8 aLo = *(const short8*)&w4S[((wv)*16 + ln)*64 + slx];
    short8 aHi = *(const short8*)&w4S[((wv + 4)*16 + ln)*64 + slx];
#pragma unroll
    for (int g = 0; g < 4; ++g) {
      short8 bv = *(const short8*)&pxb[(g*16 + ln)*64 + slx];
      accL[g] = __builtin_amdgcn_mfma_f32_16x16x32_bf16(aLo, bv, accL[g], 0, 0, 0);
      accH[g] = __builtin_amdgcn_mfma_f32_16x16x32_bf16(aHi, bv, accH[g], 0, 0, 0);
    }
  }
  __syncthreads();          // all w4 reads of pxb done
  // SimpleGate -> pxb (swizzled)
#pragma unroll
  for (int g = 0; g < 4; ++g) {
    int pxd = g*16 + ln;
    float v[4];
#pragma unroll
    for (int rg = 0; rg < 4; ++rg) v[rg] = accL[g][rg] * accH[g][rg];
    int base = pxd*64 + (((2*wv + (lk >> 1)) ^ (pxd & 7)) << 3) + (lk & 1)*4;
    *(uint2*)&pxb[base] = make_uint2(pk2(v[0], v[1]), pk2(v[2], v[3]));
  }
  __syncthreads();
  // w5 GEMM
  f32x4 acc2[4];
#pragma unroll
  for (int g = 0; g < 4; ++g)
#pragma unroll
    for (int rg = 0; rg < 4; ++rg) acc2[g][rg] = b5l[wv*16 + lk*4 + rg];
#pragma unroll
  for (int ch = 0; ch < 2; ++ch) {
    int slx = ((ch*4 + lk) ^ (ln & 7)) << 3;
    short8 a = *(const short8*)&w5S[(wv*16 + ln)*64 + slx];
#pragma unroll
    for (int g = 0; g < 4; ++g) {
      short8 bv = *(const short8*)&pxb[(g*16 + ln)*64 + slx];
      acc2[g] = __builtin_amdgcn_mfma_f32_16x16x32_bf16(a, bv, acc2[g], 0, 0, 0);
    }
  }
  float* op = outp + ((size_t)b*64*HH + h)*WW + w0;
#pragma unroll
  for (int g = 0; g < 4; ++g) {
    int pxd = g*16 + ln;
#pragma unroll
    for (int rg = 0; rg < 4; ++rg) {
      int oc = wv*16 + lk*4 + rg;
      op[(size_t)oc*HWH + pxd] = yb[oc*64 + pxd] + acc2[g][rg]*gml[oc];
    }
  }
}

extern "C" void kernel_launch(void* const* d_in, const int* in_sizes, int n_in,
                              void* d_out, int out_size, void* d_ws, size_t ws_size,
                              hipStream_t stream) {
  (void)in_sizes; (void)n_in; (void)out_size; (void)ws_size;
  const float* inp  = (const float*)d_in[0];
  const float* v    = (const float*)d_in[1];
  const float* w1   = (const float*)d_in[2];
  const float* b1   = (const float*)d_in[3];
  const float* w2   = (const float*)d_in[4];
  const float* b2   = (const float*)d_in[5];
  const float* w3   = (const float*)d_in[6];
  const float* b3   = (const float*)d_in[7];
  const float* wsca = (const float*)d_in[8];
  const float* bsca = (const float*)d_in[9];
  const float* w4   = (const float*)d_in[10];
  const float* b4   = (const float*)d_in[11];
  const float* w5   = (const float*)d_in[12];
  const float* b5   = (const float*)d_in[13];
  const float* n1w  = (const float*)d_in[14];
  const float* n1b  = (const float*)d_in[15];
  const float* n2w  = (const float*)d_in[16];
  const float* n2b  = (const float*)d_in[17];
  const float* beta = (const float*)d_in[18];
  const float* gamma= (const float*)d_in[19];

  // ws layout: f32 biases+pool, then bf16 weights/activations (~139 MB)
  float* wsf  = (float*)d_ws;
  float* pool = wsf;                    // [2][64]
  float* ab1  = wsf + 128;              // [72][128]
  float* ab2  = ab1 + 9216;
  float* ab4  = ab2 + 9216;
  float* abscaf = ab4 + 9216;           // [72][64]
  float* ab3  = abscaf + 4608;
  float* ab5  = ab3 + 4608;
  bf16* aw1b  = (bf16*)(ab5 + 4608);    // [72][128][64] swz
  bf16* a4b   = aw1b + 589824;          // [72][128][64] swz
  bf16* ascab = a4b + 589824;           // [72][64][64] swz
  bf16* a3b   = ascab + 294912;
  bf16* a5b   = a3b + 294912;
  bf16* aw2   = a5b + 294912;           // [72][9][128][128] swz
  bf16* x1    = aw2 + 10616832;         // [2][384][384][128] pixel-major
  bf16* kxb   = x1 + 37748736;          // [2][384][384][64] pixel-major
  float* out0 = (float*)d_out;
  float* yws  = out0;                   // y aliases d_out (channel-major)

  hipMemsetAsync(pool, 0, 128*sizeof(float), stream);
  k_prep<<<dim3(576), dim3(256), 0, stream>>>(v, w1, b1, w2, b2, w3, b3, wsca, bsca,
      w4, b4, w5, b5, aw1b, a4b, ascab, a3b, a5b, ab1, ab2, ab4, abscaf, ab3, ab5, aw2);
  k_ln_conv1<<<dim3(4608), dim3(256), 0, stream>>>(inp, aw1b, ab1, n1w, n1b, x1);
  k_conv2m<<<dim3(2304), dim3(256), 0, stream>>>(x1, aw2, ab2, kxb, pool);
  k_post1<<<dim3(4608), dim3(256), 0, stream>>>(kxb, inp, pool, ascab, abscaf, a3b, ab3, beta, yws);
  k_post2<<<dim3(4608), dim3(256), 0, stream>>>(yws, a4b, ab4, a5b, ab5, n2w, n2b, gamma, out0);
  hipMemcpyAsync((char*)d_out + (size_t)18874368*4, d_in[1], 360*4,
                 hipMemcpyDeviceToDevice, stream);
}

// Round 6
// 471.611 us; speedup vs baseline: 7.5790x; 1.1284x over previous
//
#include <hip/hip_runtime.h>
#include <hip/hip_bf16.h>

typedef __hip_bfloat16 bf16;
typedef unsigned short u16t;
typedef unsigned int u32t;
typedef __attribute__((ext_vector_type(8))) short short8;
typedef __attribute__((ext_vector_type(4))) float f32x4;

#define HH 384
#define WW 384
#define HWH 147456
#define EPSV 1e-6f

__device__ __forceinline__ u32t pk2(float a, float b) {
  bf16 lo = __float2bfloat16(a), hi = __float2bfloat16(b);
  return ((u32t)(*(u16t*)&hi) << 16) | (u32t)(*(u16t*)&lo);
}

// ---------------- prep: per-patch aggregated weights ----------------
// All 1x1 weights emitted bf16 PRE-SWIZZLED: [oc][64ic], elem stored at
// oc*64 + ((ic>>3)^(oc&7))*8 + (ic&7)   (128B rows, bank-balanced b128 reads)
// aw2 (3x3): [n][pos 9][half 2][oc 128][64ic] bf16, slot8 ^ (oc&7) swizzle
__global__ __launch_bounds__(256) void k_prep(
    const float* __restrict__ v,
    const float* __restrict__ w1, const float* __restrict__ b1,
    const float* __restrict__ w2, const float* __restrict__ b2,
    const float* __restrict__ w3, const float* __restrict__ b3,
    const float* __restrict__ wsca, const float* __restrict__ bsca,
    const float* __restrict__ w4, const float* __restrict__ b4,
    const float* __restrict__ w5, const float* __restrict__ b5,
    bf16* __restrict__ aw1b, bf16* __restrict__ a4b, bf16* __restrict__ ascab,
    bf16* __restrict__ a3b, bf16* __restrict__ a5b,
    float* __restrict__ ab1, float* __restrict__ ab2, float* __restrict__ ab4,
    float* __restrict__ abscaf, float* __restrict__ ab3, float* __restrict__ ab5,
    bf16* __restrict__ aw2) {
  int bid = blockIdx.x;
  int n = bid >> 3, sc = bid & 7;
  int b = n / 36, ph = (n % 36) / 6, pw = n % 6;
  float vr[5];
#pragma unroll
  for (int k = 0; k < 5; ++k) vr[k] = v[((b*5 + k)*6 + ph)*6 + pw];
  int t = threadIdx.x;
  // aw1b / a4b: [128][64]
  for (int j = sc*1024 + t; j < sc*1024 + 1024; j += 256) {
    float s1 = 0.f, s4 = 0.f;
#pragma unroll
    for (int k = 0; k < 5; ++k) {
      s1 += vr[k] * w1[k*8192 + j];
      s4 += vr[k] * w4[k*8192 + j];
    }
    int oc = j >> 6, ic = j & 63;
    int idx = n*8192 + oc*64 + (((ic >> 3) ^ (oc & 7)) << 3) + (ic & 7);
    aw1b[idx] = __float2bfloat16(s1);
    a4b[idx]  = __float2bfloat16(s4);
  }
  // ascab / a3b / a5b: [64][64]
  for (int j = sc*512 + t; j < sc*512 + 512; j += 256) {
    float ss = 0.f, s3 = 0.f, s5 = 0.f;
#pragma unroll
    for (int k = 0; k < 5; ++k) {
      ss += vr[k] * wsca[k*4096 + j];
      s3 += vr[k] * w3[k*4096 + j];
      s5 += vr[k] * w5[k*4096 + j];
    }
    int oc = j >> 6, ic = j & 63;
    int idx = n*4096 + oc*64 + (((ic >> 3) ^ (oc & 7)) << 3) + (ic & 7);
    ascab[idx] = __float2bfloat16(ss);
    a3b[idx]   = __float2bfloat16(s3);
    a5b[idx]   = __float2bfloat16(s5);
  }
  if (sc == 0) {
    if (t < 128) {
      float s1 = 0.f, s2 = 0.f, s4 = 0.f;
#pragma unroll
      for (int k = 0; k < 5; ++k) {
        s1 += vr[k] * b1[k*128 + t];
        s2 += vr[k] * b2[k*128 + t];
        s4 += vr[k] * b4[k*128 + t];
      }
      ab1[n*128 + t] = s1; ab2[n*128 + t] = s2; ab4[n*128 + t] = s4;
    } else if (t < 192) {
      int c = t - 128;
      float ss = 0.f, s3 = 0.f, s5 = 0.f;
#pragma unroll
      for (int k = 0; k < 5; ++k) {
        ss += vr[k] * bsca[k*64 + c];
        s3 += vr[k] * b3[k*64 + c];
        s5 += vr[k] * b5[k*64 + c];
      }
      abscaf[n*64 + c] = ss; ab3[n*64 + c] = s3; ab5[n*64 + c] = s5;
    }
  }
  // aw2: j = ((oc*128 + ic)*3 + kh)*3 + kw
  for (int j = sc*18432 + t; j < sc*18432 + 18432; j += 256) {
    float s = 0.f;
#pragma unroll
    for (int k = 0; k < 5; ++k) s += vr[k] * w2[(size_t)k*147456 + j];
    int oc = j / 1152;
    int rr = j - oc*1152;
    int ic = rr / 9;
    int tt = rr - ic*9;
    int half = ic >> 6;
    int sl = (ic >> 3) & 7;
    aw2[(size_t)n*147456 + ((size_t)((tt*2 + half)*128 + oc) << 6)
        + (((sl ^ (oc & 7)) << 3) | (ic & 7))] = __float2bfloat16(s);
  }
}

// ---------------- LN + conv1 (MFMA 1x1, 64->128) ----------------
// grid 4608, 256 threads. x1 pixel-major [b][h][w][128].
__global__ __launch_bounds__(256) void k_ln_conv1(
    const float* __restrict__ inp, const bf16* __restrict__ aw1b,
    const float* __restrict__ ab1, const float* __restrict__ n1w,
    const float* __restrict__ n1b, bf16* __restrict__ x1) {
  __shared__ alignas(16) float xl[4096];          // input tile; reused as bf16 stage
  __shared__ alignas(16) u16t wA[8192];           // [128][64] swz
  __shared__ alignas(16) u16t lnb[4096];          // [64px][64ic] swz
  __shared__ float bl[128];
  __shared__ float gl[64], bel[64];
  __shared__ float ps[4][64], ps2[4][64];
  int bid = blockIdx.x;
  int b = bid / 2304; int rem = bid % 2304; int h = rem / 6; int pw = rem % 6;
  int ph = h >> 6; int n = (b*6 + ph)*6 + pw; int w0 = pw*64;
  int t = threadIdx.x;
  for (int j = t; j < 1024; j += 256)
    ((uint4*)wA)[j] = ((const uint4*)(aw1b + (size_t)n*8192))[j];
  if (t < 128) bl[t] = ab1[n*128 + t];
  if (t < 64) { gl[t] = n1w[t]; bel[t] = n1b[t]; }
  const float* ip = inp + ((size_t)b*64*HH + h)*WW + w0;
  for (int j = t; j < 4096; j += 256) {
    int c = j >> 6, px = j & 63;
    xl[j] = ip[(size_t)c*HWH + px];
  }
  __syncthreads();
  int px = t & 63, part = t >> 6;
  {
    float s = 0.f, s2 = 0.f;
    for (int c = part*16; c < part*16 + 16; ++c) { float xv = xl[c*64 + px]; s += xv; s2 += xv*xv; }
    ps[part][px] = s; ps2[part][px] = s2;
  }
  __syncthreads();
  float mu = (ps[0][px] + ps[1][px] + ps[2][px] + ps[3][px]) * (1.f/64.f);
  float var = (ps2[0][px] + ps2[1][px] + ps2[2][px] + ps2[3][px]) * (1.f/64.f) - mu*mu;
  float rs = rsqrtf(fmaxf(var, 0.f) + EPSV);
  {
    float lv[16];
#pragma unroll
    for (int cc = 0; cc < 16; ++cc) {
      int c = part*16 + cc;
      lv[cc] = (xl[c*64 + px] - mu) * rs * gl[c] + bel[c];
    }
    *(uint4*)&lnb[px*64 + (((part*2) ^ (px&7)) << 3)] =
        make_uint4(pk2(lv[0],lv[1]), pk2(lv[2],lv[3]), pk2(lv[4],lv[5]), pk2(lv[6],lv[7]));
    *(uint4*)&lnb[px*64 + (((part*2+1) ^ (px&7)) << 3)] =
        make_uint4(pk2(lv[8],lv[9]), pk2(lv[10],lv[11]), pk2(lv[12],lv[13]), pk2(lv[14],lv[15]));
  }
  __syncthreads();
  int wv = t >> 6, l = t & 63, ln = l & 15, lk = l >> 4;
  f32x4 acc[2][4];
#pragma unroll
  for (int i = 0; i < 2; ++i)
#pragma unroll
    for (int g = 0; g < 4; ++g)
#pragma unroll
      for (int rg = 0; rg < 4; ++rg)
        acc[i][g][rg] = bl[(2*wv + i)*16 + lk*4 + rg];
#pragma unroll
  for (int ch = 0; ch < 2; ++ch) {
    int slx = ((ch*4 + lk) ^ (ln & 7)) << 3;
    short8 a0 = *(const short8*)&wA[((2*wv + 0)*16 + ln)*64 + slx];
    short8 a1 = *(const short8*)&wA[((2*wv + 1)*16 + ln)*64 + slx];
#pragma unroll
    for (int g = 0; g < 4; ++g) {
      short8 bv = *(const short8*)&lnb[(g*16 + ln)*64 + slx];
      acc[0][g] = __builtin_amdgcn_mfma_f32_16x16x32_bf16(a0, bv, acc[0][g], 0, 0, 0);
      acc[1][g] = __builtin_amdgcn_mfma_f32_16x16x32_bf16(a1, bv, acc[1][g], 0, 0, 0);
    }
  }
  // D -> LDS stage (swizzled 8B granules), then coalesced copy-out
  u16t* stg = (u16t*)xl;   // 64px x 128oc bf16 = 16KB
#pragma unroll
  for (int i = 0; i < 2; ++i)
#pragma unroll
    for (int g = 0; g < 4; ++g) {
      int pxd = g*16 + ln;
      int g8 = (2*wv + i)*4 + lk;             // oc>>2
      int st = g8 ^ (pxd & 15);
      *(uint2*)&stg[pxd*128 + (st << 2)] =
          make_uint2(pk2(acc[i][g][0], acc[i][g][1]), pk2(acc[i][g][2], acc[i][g][3]));
    }
  __syncthreads();
  bf16* xp = x1 + (((size_t)b*HH + h)*WW + w0)*128;
  for (int j = t; j < 2048; j += 256) {
    int pxd = j >> 5, gs = j & 31;
    uint2 val = *(uint2*)&stg[pxd*128 + (gs << 2)];
    *(uint2*)(xp + (size_t)pxd*128 + ((gs ^ (pxd & 15)) << 2)) = val;
  }
}

// ---------------- conv2 via MFMA implicit GEMM + SG + pool ----------------
// grid = 2304 blocks, 256 threads (4 waves). LDS ~67.5 KB -> 2 blocks/CU.
// K split into 2 ic-halves of 64; acc persists across halves.
__global__ __launch_bounds__(256) void k_conv2m(
    const bf16* __restrict__ x1, const bf16* __restrict__ aw2,
    const float* __restrict__ ab2, bf16* __restrict__ kx, float* __restrict__ pool) {
  __shared__ alignas(16) u16t xs[4*66*64];      // 33792 B; reused as kx stage
  __shared__ alignas(16) u16t wsA[8192];        // 16 KB
  __shared__ alignas(16) u16t wsB[8192];        // 16 KB
  __shared__ float pool_l[64];
  __shared__ float bias_l[128];
  int bid = blockIdx.x;
  int n = bid >> 5, rp = bid & 31;
  int b = n / 36, ph = (n % 36) / 6, pw = n % 6;
  int r0 = rp * 2;
  int t = threadIdx.x;
  if (t < 64) pool_l[t] = 0.f;
  if (t < 128) bias_l[t] = ab2[n*128 + t];

  const bf16* xbase = x1 + ((((size_t)b*HH + ph*64)*WW + pw*64) << 7);
  const bf16* wbase = aw2 + (size_t)n*147456;
  int wv = t >> 6, l = t & 63;
  int ln = l & 15, lk = l >> 4;
  int rr = wv >> 1;
  int cb0 = (wv & 1) * 32;
  f32x4 acc[8][2];
#pragma unroll
  for (int f = 0; f < 8; ++f)
#pragma unroll
    for (int g = 0; g < 2; ++g) acc[f][g] = (f32x4){0.f, 0.f, 0.f, 0.f};

  for (int icc = 0; icc < 2; ++icc) {
    __syncthreads();   // prior-half xs/wsA readers done before restage
    // stage xs half: 4 rows x 66 cols x 64 ic (slot8 ^ (c&7) swizzle)
    for (int j = t; j < 2112; j += 256) {
      int s_st = j & 7;
      int rc = j >> 3;
      int c = rc % 66, r = rc / 66;
      int gr = r0 + r - 1, gc = c - 1;
      uint4 val = make_uint4(0u, 0u, 0u, 0u);
      if (gr >= 0 && gr < 64 && gc >= 0 && gc < 64) {
        int s_orig = s_st ^ (c & 7);
        val = *(const uint4*)(xbase + (((size_t)gr*WW + gc) << 7) + icc*64 + s_orig*8);
      }
      *(uint4*)&xs[j*8] = val;
    }
    // stage ws[pos=0][icc]
    {
      const uint4* wp = (const uint4*)(wbase + (size_t)icc*8192);
#pragma unroll
      for (int i = 0; i < 4; ++i) ((uint4*)wsA)[i*256 + t] = wp[i*256 + t];
    }
    __syncthreads();

    uint4 stgld[4];
    for (int pos = 0; pos < 9; ++pos) {
      const u16t* wcur = (pos & 1) ? wsB : wsA;
      u16t* wnx = (pos & 1) ? wsA : wsB;
      int dh = pos / 3, dw = pos - dh*3;
      if (pos < 8) {
        const uint4* wp = (const uint4*)(wbase + (size_t)((pos + 1)*2 + icc)*8192);
#pragma unroll
        for (int i = 0; i < 4; ++i) stgld[i] = wp[i*256 + t];
      }
#pragma unroll
      for (int ch = 0; ch < 2; ++ch) {
        short8 af[8];
#pragma unroll
        for (int f = 0; f < 8; ++f) {
          int oc = f*16 + ln;
          int slot = (ch*4 + lk) ^ (oc & 7);
          af[f] = *(const short8*)&wcur[oc*64 + slot*8];
        }
#pragma unroll
        for (int g = 0; g < 2; ++g) {
          int cl = cb0 + g*16 + ln + dw;
          int row = rr + dh;
          int slot = (ch*4 + lk) ^ (cl & 7);
          short8 bfv = *(const short8*)&xs[(row*66 + cl)*64 + slot*8];
#pragma unroll
          for (int f = 0; f < 8; ++f)
            acc[f][g] = __builtin_amdgcn_mfma_f32_16x16x32_bf16(af[f], bfv, acc[f][g], 0, 0, 0);
        }
      }
      if (pos < 8) {
#pragma unroll
        for (int i = 0; i < 4; ++i) *(uint4*)&wnx[(i*256 + t)*8] = stgld[i];
        __syncthreads();   // wnx last read at pos-1 (before this point); safe
      }
    }
  }

  __syncthreads();                 // all xs reads done -> reuse xs as stage
  u16t* stg = xs;                  // [2 rows][64 cols][64 q] bf16 = 16KB
  float psum[4][4];
#pragma unroll
  for (int f = 0; f < 4; ++f)
#pragma unroll
    for (int rg = 0; rg < 4; ++rg) psum[f][rg] = 0.f;
#pragma unroll
  for (int f = 0; f < 4; ++f) {
#pragma unroll
    for (int g = 0; g < 2; ++g) {
      f32x4 lo = acc[f][g], hi = acc[f + 4][g];
      int col = cb0 + g*16 + ln;
      float kv[4];
#pragma unroll
      for (int rg = 0; rg < 4; ++rg) {
        int q = f*16 + lk*4 + rg;
        kv[rg] = (lo[rg] + bias_l[q]) * (hi[rg] + bias_l[64 + q]);
        psum[f][rg] += kv[rg];
      }
      int gq = f*4 + lk;
      int st = gq ^ (col & 15);
      *(uint2*)&stg[rr*4096 + col*64 + (st << 2)] =
          make_uint2(pk2(kv[0], kv[1]), pk2(kv[2], kv[3]));
    }
  }
#pragma unroll
  for (int f = 0; f < 4; ++f)
#pragma unroll
    for (int rg = 0; rg < 4; ++rg) {
      float s = psum[f][rg];
      s += __shfl_xor(s, 1); s += __shfl_xor(s, 2);
      s += __shfl_xor(s, 4); s += __shfl_xor(s, 8);
      if (ln == 0) atomicAdd(&pool_l[f*16 + lk*4 + rg], s);
    }
  __syncthreads();
  for (int j = t; j < 2048; j += 256) {
    int rr2 = j >> 10, remj = j & 1023, col = remj >> 4, gs = remj & 15;
    uint2 val = *(uint2*)&stg[rr2*4096 + col*64 + (gs << 2)];
    int hh2 = ph*64 + r0 + rr2;
    int gcol = pw*64 + col;
    *(uint2*)(kx + ((((size_t)b*HH + hh2)*WW + gcol) << 6) + ((gs ^ (col & 15)) << 2)) = val;
  }
  if (t < 64) atomicAdd(&pool[b*64 + t], pool_l[t]);
}

// ---------------- post1 (MFMA): sca conv, pooled-mul, w3 conv, y = inp + x*beta ----------------
__global__ __launch_bounds__(256) void k_post1(
    const bf16* __restrict__ kxg, const float* __restrict__ inp,
    const float* __restrict__ pool,
    const bf16* __restrict__ ascab, const float* __restrict__ abscaf,
    const bf16* __restrict__ a3b, const float* __restrict__ ab3,
    const float* __restrict__ beta, float* __restrict__ yws) {
  __shared__ alignas(16) u16t wS[4096];
  __shared__ alignas(16) u16t w3S[4096];
  __shared__ alignas(16) u16t B1[4096];
  __shared__ alignas(16) u16t B2[4096];
  __shared__ float bsl[64], b3l[64], pol[64], betal[64];
  int bid = blockIdx.x;
  int b = bid / 2304; int rem = bid % 2304; int h = rem / 6; int pw = rem % 6;
  int ph = h >> 6; int n = (b*6 + ph)*6 + pw; int w0 = pw*64;
  int t = threadIdx.x;
  for (int j = t; j < 512; j += 256) {
    ((uint4*)wS)[j]  = ((const uint4*)(ascab + (size_t)n*4096))[j];
    ((uint4*)w3S)[j] = ((const uint4*)(a3b + (size_t)n*4096))[j];
  }
  if (t < 64) {
    bsl[t] = abscaf[n*64 + t];
    b3l[t] = ab3[n*64 + t];
    pol[t] = pool[b*64 + t] * (1.0f/147456.0f);
    betal[t] = beta[t];
  }
  const bf16* kxp = kxg + (((size_t)b*HH + h)*WW + w0)*64;
  for (int j = t; j < 512; j += 256) {
    int px = j >> 3, sl = j & 7;
    *(uint4*)&B1[px*64 + ((sl ^ (px & 7)) << 3)] = *(const uint4*)(kxp + px*64 + sl*8);
  }
  __syncthreads();
  int wv = t >> 6, l = t & 63, ln = l & 15, lk = l >> 4;
  // GEMM1: sca
  f32x4 acc[4];
#pragma unroll
  for (int g = 0; g < 4; ++g)
#pragma unroll
    for (int rg = 0; rg < 4; ++rg) acc[g][rg] = bsl[wv*16 + lk*4 + rg];
#pragma unroll
  for (int ch = 0; ch < 2; ++ch) {
    int slx = ((ch*4 + lk) ^ (ln & 7)) << 3;
    short8 a = *(const short8*)&wS[(wv*16 + ln)*64 + slx];
#pragma unroll
    for (int g = 0; g < 4; ++g) {
      short8 bv = *(const short8*)&B1[(g*16 + ln)*64 + slx];
      acc[g] = __builtin_amdgcn_mfma_f32_16x16x32_bf16(a, bv, acc[g], 0, 0, 0);
    }
  }
  // scale by pooled mean, write B2 (swizzled)
#pragma unroll
  for (int g = 0; g < 4; ++g) {
    int px = g*16 + ln;
    float v[4];
#pragma unroll
    for (int rg = 0; rg < 4; ++rg) v[rg] = acc[g][rg] * pol[wv*16 + lk*4 + rg];
    int base = px*64 + (((2*wv + (lk >> 1)) ^ (px & 7)) << 3) + (lk & 1)*4;
    *(uint2*)&B2[base] = make_uint2(pk2(v[0], v[1]), pk2(v[2], v[3]));
  }
  __syncthreads();
  // GEMM2: w3
  f32x4 acc2[4];
#pragma unroll
  for (int g = 0; g < 4; ++g)
#pragma unroll
    for (int rg = 0; rg < 4; ++rg) acc2[g][rg] = b3l[wv*16 + lk*4 + rg];
#pragma unroll
  for (int ch = 0; ch < 2; ++ch) {
    int slx = ((ch*4 + lk) ^ (ln & 7)) << 3;
    short8 a = *(const short8*)&w3S[(wv*16 + ln)*64 + slx];
#pragma unroll
    for (int g = 0; g < 4; ++g) {
      short8 bv = *(const short8*)&B2[(g*16 + ln)*64 + slx];
      acc2[g] = __builtin_amdgcn_mfma_f32_16x16x32_bf16(a, bv, acc2[g], 0, 0, 0);
    }
  }
  const float* inpp = inp + ((size_t)b*64*HH + h)*WW + w0;
  float* yp = yws + ((size_t)b*64*HH + h)*WW + w0;
#pragma unroll
  for (int g = 0; g < 4; ++g) {
    int px = g*16 + ln;
#pragma unroll
    for (int rg = 0; rg < 4; ++rg) {
      int oc = wv*16 + lk*4 + rg;
      yp[(size_t)oc*HWH + px] = inpp[(size_t)oc*HWH + px] + acc2[g][rg]*betal[oc];
    }
  }
}

// ---------------- post2 (MFMA): LN(y), w4, SG, w5, out = y + x*gamma ----------------
__global__ __launch_bounds__(256) void k_post2(
    const float* __restrict__ yws,
    const bf16* __restrict__ a4b, const float* __restrict__ ab4,
    const bf16* __restrict__ a5b, const float* __restrict__ ab5,
    const float* __restrict__ n2w, const float* __restrict__ n2b,
    const float* __restrict__ gamma, float* __restrict__ outp) {
  __shared__ alignas(16) float yb[4096];
  __shared__ alignas(16) u16t w4S[8192];
  __shared__ alignas(16) u16t w5S[4096];
  __shared__ alignas(16) u16t pxb[4096];   // LN out, then SG out
  __shared__ float ps[4][64], ps2[4][64];
  __shared__ float b4l[128], b5l[64], gl[64], bel[64], gml[64];
  int bid = blockIdx.x;
  int b = bid / 2304; int rem = bid % 2304; int h = rem / 6; int pw = rem % 6;
  int ph = h >> 6; int n = (b*6 + ph)*6 + pw; int w0 = pw*64;
  int t = threadIdx.x;
  for (int j = t; j < 1024; j += 256)
    ((uint4*)w4S)[j] = ((const uint4*)(a4b + (size_t)n*8192))[j];
  for (int j = t; j < 512; j += 256)
    ((uint4*)w5S)[j] = ((const uint4*)(a5b + (size_t)n*4096))[j];
  if (t < 128) b4l[t] = ab4[n*128 + t];
  if (t < 64) {
    b5l[t] = ab5[n*64 + t];
    gl[t]  = n2w[t];
    bel[t] = n2b[t];
    gml[t] = gamma[t];
  }
  const float* yp = yws + ((size_t)b*64*HH + h)*WW + w0;
  for (int j = t; j < 4096; j += 256) {
    int c = j >> 6, px = j & 63;
    yb[j] = yp[(size_t)c*HWH + px];
  }
  __syncthreads();
  int px = t & 63, part = t >> 6;
  {
    float s = 0.f, s2 = 0.f;
    for (int c = part*16; c < part*16 + 16; ++c) { float yv = yb[c*64 + px]; s += yv; s2 += yv*yv; }
    ps[part][px] = s; ps2[part][px] = s2;
  }
  __syncthreads();
  float mu = (ps[0][px] + ps[1][px] + ps[2][px] + ps[3][px]) * (1.f/64.f);
  float var = (ps2[0][px] + ps2[1][px] + ps2[2][px] + ps2[3][px]) * (1.f/64.f) - mu*mu;
  float rs = rsqrtf(fmaxf(var, 0.f) + EPSV);
  {
    float lv[16];
#pragma unroll
    for (int cc = 0; cc < 16; ++cc) {
      int c = part*16 + cc;
      lv[cc] = (yb[c*64 + px] - mu) * rs * gl[c] + bel[c];
    }
    *(uint4*)&pxb[px*64 + (((part*2) ^ (px&7)) << 3)] =
        make_uint4(pk2(lv[0],lv[1]), pk2(lv[2],lv[3]), pk2(lv[4],lv[5]), pk2(lv[6],lv[7]));
    *(uint4*)&pxb[px*64 + (((part*2+1) ^ (px&7)) << 3)] =
        make_uint4(pk2(lv[8],lv[9]), pk2(lv[10],lv[11]), pk2(lv[12],lv[13]), pk2(lv[14],lv[15]));
  }
  __syncthreads();
  int wv = t >> 6, l = t & 63, ln = l & 15, lk = l >> 4;
  // w4 GEMM: wave wv owns oc-frags {wv, wv+4} so SG pairs share a lane
  f32x4 accL[4], accH[4];
#pragma unroll
  for (int g = 0; g < 4; ++g)
#pragma unroll
    for (int rg = 0; rg < 4; ++rg) {
      accL[g][rg] = b4l[wv*16 + lk*4 + rg];
      accH[g][rg] = b4l[64 + wv*16 + lk*4 + rg];
    }
#pragma unroll
  for (int ch = 0; ch < 2; ++ch) {
    int slx = ((ch*4 + lk) ^ (ln & 7)) << 3;
    short8 aLo = *(const short8*)&w4S[((wv)*16 + ln)*64 + slx];
    short8 aHi = *(const short8*)&w4S[((wv + 4)*16 + ln)*64 + slx];
#pragma unroll
    for (int g = 0; g < 4; ++g) {
      short8 bv = *(const short8*)&pxb[(g*16 + ln)*64 + slx];
      accL[g] = __builtin_amdgcn_mfma_f32_16x16x32_bf16(aLo, bv, accL[g], 0, 0, 0);
      accH[g] = __builtin_amdgcn_mfma_f32_16x16x32_bf16(aHi, bv, accH[g], 0, 0, 0);
    }
  }
  __syncthreads();          // all w4 reads of pxb done
  // SimpleGate -> pxb (swizzled)
#pragma unroll
  for (int g = 0; g < 4; ++g) {
    int pxd = g*16 + ln;
    float v[4];
#pragma unroll
    for (int rg = 0; rg < 4; ++rg) v[rg] = accL[g][rg] * accH[g][rg];
    int base = pxd*64 + (((2*wv + (lk >> 1)) ^ (pxd & 7)) << 3) + (lk & 1)*4;
    *(uint2*)&pxb[base] = make_uint2(pk2(v[0], v[1]), pk2(v[2], v[3]));
  }
  __syncthreads();
  // w5 GEMM
  f32x4 acc2[4];
#pragma unroll
  for (int g = 0; g < 4; ++g)
#pragma unroll
    for (int rg = 0; rg < 4; ++rg) acc2[g][rg] = b5l[wv*16 + lk*4 + rg];
#pragma unroll
  for (int ch = 0; ch < 2; ++ch) {
    int slx = ((ch*4 + lk) ^ (ln & 7)) << 3;
    short8 a = *(const short8*)&w5S[(wv*16 + ln)*64 + slx];
#pragma unroll
    for (int g = 0; g < 4; ++g) {
      short8 bv = *(const short8*)&pxb[(g*16 + ln)*64 + slx];
      acc2[g] = __builtin_amdgcn_mfma_f32_16x16x32_bf16(a, bv, acc2[g], 0, 0, 0);
    }
  }
  float* op = outp + ((size_t)b*64*HH + h)*WW + w0;
#pragma unroll
  for (int g = 0; g < 4; ++g) {
    int pxd = g*16 + ln;
#pragma unroll
    for (int rg = 0; rg < 4; ++rg) {
      int oc = wv*16 + lk*4 + rg;
      op[(size_t)oc*HWH + pxd] = yb[oc*64 + pxd] + acc2[g][rg]*gml[oc];
    }
  }
}

extern "C" void kernel_launch(void* const* d_in, const int* in_sizes, int n_in,
                              void* d_out, int out_size, void* d_ws, size_t ws_size,
                              hipStream_t stream) {
  (void)in_sizes; (void)n_in; (void)out_size; (void)ws_size;
  const float* inp  = (const float*)d_in[0];
  const float* v    = (const float*)d_in[1];
  const float* w1   = (const float*)d_in[2];
  const float* b1   = (const float*)d_in[3];
  const float* w2   = (const float*)d_in[4];
  const float* b2   = (const float*)d_in[5];
  const float* w3   = (const float*)d_in[6];
  const float* b3   = (const float*)d_in[7];
  const float* wsca = (const float*)d_in[8];
  const float* bsca = (const float*)d_in[9];
  const float* w4   = (const float*)d_in[10];
  const float* b4   = (const float*)d_in[11];
  const float* w5   = (const float*)d_in[12];
  const float* b5   = (const float*)d_in[13];
  const float* n1w  = (const float*)d_in[14];
  const float* n1b  = (const float*)d_in[15];
  const float* n2w  = (const float*)d_in[16];
  const float* n2b  = (const float*)d_in[17];
  const float* beta = (const float*)d_in[18];
  const float* gamma= (const float*)d_in[19];

  // ws layout: f32 biases+pool, then bf16 weights/activations (~139 MB)
  float* wsf  = (float*)d_ws;
  float* pool = wsf;                    // [2][64]
  float* ab1  = wsf + 128;              // [72][128]
  float* ab2  = ab1 + 9216;
  float* ab4  = ab2 + 9216;
  float* abscaf = ab4 + 9216;           // [72][64]
  float* ab3  = abscaf + 4608;
  float* ab5  = ab3 + 4608;
  bf16* aw1b  = (bf16*)(ab5 + 4608);    // [72][128][64] swz
  bf16* a4b   = aw1b + 589824;          // [72][128][64] swz
  bf16* ascab = a4b + 589824;           // [72][64][64] swz
  bf16* a3b   = ascab + 294912;
  bf16* a5b   = a3b + 294912;
  bf16* aw2   = a5b + 294912;           // [72][9][2][128][64] swz
  bf16* x1    = aw2 + 10616832;         // [2][384][384][128] pixel-major
  bf16* kxb   = x1 + 37748736;          // [2][384][384][64] pixel-major
  float* out0 = (float*)d_out;
  float* yws  = out0;                   // y aliases d_out (channel-major)

  hipMemsetAsync(pool, 0, 128*sizeof(float), stream);
  k_prep<<<dim3(576), dim3(256), 0, stream>>>(v, w1, b1, w2, b2, w3, b3, wsca, bsca,
      w4, b4, w5, b5, aw1b, a4b, ascab, a3b, a5b, ab1, ab2, ab4, abscaf, ab3, ab5, aw2);
  k_ln_conv1<<<dim3(4608), dim3(256), 0, stream>>>(inp, aw1b, ab1, n1w, n1b, x1);
  k_conv2m<<<dim3(2304), dim3(256), 0, stream>>>(x1, aw2, ab2, kxb, pool);
  k_post1<<<dim3(4608), dim3(256), 0, stream>>>(kxb, inp, pool, ascab, abscaf, a3b, ab3, beta, yws);
  k_post2<<<dim3(4608), dim3(256), 0, stream>>>(yws, a4b, ab4, a5b, ab5, n2w, n2b, gamma, out0);
  hipMemcpyAsync((char*)d_out + (size_t)18874368*4, d_in[1], 360*4,
                 hipMemcpyDeviceToDevice, stream);
}

// Round 7
// 442.916 us; speedup vs baseline: 8.0700x; 1.0648x over previous
//
#include <hip/hip_runtime.h>
#include <hip/hip_bf16.h>

typedef __hip_bfloat16 bf16;
typedef unsigned short u16t;
typedef unsigned int u32t;
typedef __attribute__((ext_vector_type(8))) short short8;
typedef __attribute__((ext_vector_type(4))) float f32x4;

#define HH 384
#define WW 384
#define HWH 147456
#define EPSV 1e-6f

__device__ __forceinline__ u32t pk2(float a, float b) {
  bf16 lo = __float2bfloat16(a), hi = __float2bfloat16(b);
  return ((u32t)(*(u16t*)&hi) << 16) | (u32t)(*(u16t*)&lo);
}

// ---------------- prep: per-patch aggregated weights ----------------
// All 1x1 weights emitted bf16 PRE-SWIZZLED: [oc][64ic], elem stored at
// oc*64 + ((ic>>3)^(oc&7))*8 + (ic&7)   (128B rows, bank-balanced b128 reads)
// aw2 (3x3): [n][pos 9][half 2][oc 128][64ic] bf16, slot8 ^ (oc&7) swizzle
__global__ __launch_bounds__(256) void k_prep(
    const float* __restrict__ v,
    const float* __restrict__ w1, const float* __restrict__ b1,
    const float* __restrict__ w2, const float* __restrict__ b2,
    const float* __restrict__ w3, const float* __restrict__ b3,
    const float* __restrict__ wsca, const float* __restrict__ bsca,
    const float* __restrict__ w4, const float* __restrict__ b4,
    const float* __restrict__ w5, const float* __restrict__ b5,
    bf16* __restrict__ aw1b, bf16* __restrict__ a4b, bf16* __restrict__ ascab,
    bf16* __restrict__ a3b, bf16* __restrict__ a5b,
    float* __restrict__ ab1, float* __restrict__ ab2, float* __restrict__ ab4,
    float* __restrict__ abscaf, float* __restrict__ ab3, float* __restrict__ ab5,
    bf16* __restrict__ aw2) {
  int bid = blockIdx.x;
  int n = bid >> 3, sc = bid & 7;
  int b = n / 36, ph = (n % 36) / 6, pw = n % 6;
  float vr[5];
#pragma unroll
  for (int k = 0; k < 5; ++k) vr[k] = v[((b*5 + k)*6 + ph)*6 + pw];
  int t = threadIdx.x;
  // aw1b / a4b: [128][64]
  for (int j = sc*1024 + t; j < sc*1024 + 1024; j += 256) {
    float s1 = 0.f, s4 = 0.f;
#pragma unroll
    for (int k = 0; k < 5; ++k) {
      s1 += vr[k] * w1[k*8192 + j];
      s4 += vr[k] * w4[k*8192 + j];
    }
    int oc = j >> 6, ic = j & 63;
    int idx = n*8192 + oc*64 + (((ic >> 3) ^ (oc & 7)) << 3) + (ic & 7);
    aw1b[idx] = __float2bfloat16(s1);
    a4b[idx]  = __float2bfloat16(s4);
  }
  // ascab / a3b / a5b: [64][64]
  for (int j = sc*512 + t; j < sc*512 + 512; j += 256) {
    float ss = 0.f, s3 = 0.f, s5 = 0.f;
#pragma unroll
    for (int k = 0; k < 5; ++k) {
      ss += vr[k] * wsca[k*4096 + j];
      s3 += vr[k] * w3[k*4096 + j];
      s5 += vr[k] * w5[k*4096 + j];
    }
    int oc = j >> 6, ic = j & 63;
    int idx = n*4096 + oc*64 + (((ic >> 3) ^ (oc & 7)) << 3) + (ic & 7);
    ascab[idx] = __float2bfloat16(ss);
    a3b[idx]   = __float2bfloat16(s3);
    a5b[idx]   = __float2bfloat16(s5);
  }
  if (sc == 0) {
    if (t < 128) {
      float s1 = 0.f, s2 = 0.f, s4 = 0.f;
#pragma unroll
      for (int k = 0; k < 5; ++k) {
        s1 += vr[k] * b1[k*128 + t];
        s2 += vr[k] * b2[k*128 + t];
        s4 += vr[k] * b4[k*128 + t];
      }
      ab1[n*128 + t] = s1; ab2[n*128 + t] = s2; ab4[n*128 + t] = s4;
    } else if (t < 192) {
      int c = t - 128;
      float ss = 0.f, s3 = 0.f, s5 = 0.f;
#pragma unroll
      for (int k = 0; k < 5; ++k) {
        ss += vr[k] * bsca[k*64 + c];
        s3 += vr[k] * b3[k*64 + c];
        s5 += vr[k] * b5[k*64 + c];
      }
      abscaf[n*64 + c] = ss; ab3[n*64 + c] = s3; ab5[n*64 + c] = s5;
    }
  }
  // aw2: j = ((oc*128 + ic)*3 + kh)*3 + kw
  for (int j = sc*18432 + t; j < sc*18432 + 18432; j += 256) {
    float s = 0.f;
#pragma unroll
    for (int k = 0; k < 5; ++k) s += vr[k] * w2[(size_t)k*147456 + j];
    int oc = j / 1152;
    int rr = j - oc*1152;
    int ic = rr / 9;
    int tt = rr - ic*9;
    int half = ic >> 6;
    int sl = (ic >> 3) & 7;
    aw2[(size_t)n*147456 + ((size_t)((tt*2 + half)*128 + oc) << 6)
        + (((sl ^ (oc & 7)) << 3) | (ic & 7))] = __float2bfloat16(s);
  }
}

// ---------------- LN + conv1 (MFMA 1x1, 64->128) ----------------
// grid 4608, 256 threads. x1 pixel-major [b][h][w][128].
__global__ __launch_bounds__(256) void k_ln_conv1(
    const float* __restrict__ inp, const bf16* __restrict__ aw1b,
    const float* __restrict__ ab1, const float* __restrict__ n1w,
    const float* __restrict__ n1b, bf16* __restrict__ x1) {
  __shared__ alignas(16) float xl[4096];          // input tile; reused as bf16 stage
  __shared__ alignas(16) u16t wA[8192];           // [128][64] swz
  __shared__ alignas(16) u16t lnb[4096];          // [64px][64ic] swz
  __shared__ float bl[128];
  __shared__ float gl[64], bel[64];
  __shared__ float ps[4][64], ps2[4][64];
  int bid = blockIdx.x;
  int b = bid / 2304; int rem = bid % 2304; int h = rem / 6; int pw = rem % 6;
  int ph = h >> 6; int n = (b*6 + ph)*6 + pw; int w0 = pw*64;
  int t = threadIdx.x;
  for (int j = t; j < 1024; j += 256)
    ((uint4*)wA)[j] = ((const uint4*)(aw1b + (size_t)n*8192))[j];
  if (t < 128) bl[t] = ab1[n*128 + t];
  if (t < 64) { gl[t] = n1w[t]; bel[t] = n1b[t]; }
  const float* ip = inp + ((size_t)b*64*HH + h)*WW + w0;
  for (int j = t; j < 4096; j += 256) {
    int c = j >> 6, px = j & 63;
    xl[j] = ip[(size_t)c*HWH + px];
  }
  __syncthreads();
  int px = t & 63, part = t >> 6;
  {
    float s = 0.f, s2 = 0.f;
    for (int c = part*16; c < part*16 + 16; ++c) { float xv = xl[c*64 + px]; s += xv; s2 += xv*xv; }
    ps[part][px] = s; ps2[part][px] = s2;
  }
  __syncthreads();
  float mu = (ps[0][px] + ps[1][px] + ps[2][px] + ps[3][px]) * (1.f/64.f);
  float var = (ps2[0][px] + ps2[1][px] + ps2[2][px] + ps2[3][px]) * (1.f/64.f) - mu*mu;
  float rs = rsqrtf(fmaxf(var, 0.f) + EPSV);
  {
    float lv[16];
#pragma unroll
    for (int cc = 0; cc < 16; ++cc) {
      int c = part*16 + cc;
      lv[cc] = (xl[c*64 + px] - mu) * rs * gl[c] + bel[c];
    }
    *(uint4*)&lnb[px*64 + (((part*2) ^ (px&7)) << 3)] =
        make_uint4(pk2(lv[0],lv[1]), pk2(lv[2],lv[3]), pk2(lv[4],lv[5]), pk2(lv[6],lv[7]));
    *(uint4*)&lnb[px*64 + (((part*2+1) ^ (px&7)) << 3)] =
        make_uint4(pk2(lv[8],lv[9]), pk2(lv[10],lv[11]), pk2(lv[12],lv[13]), pk2(lv[14],lv[15]));
  }
  __syncthreads();
  int wv = t >> 6, l = t & 63, ln = l & 15, lk = l >> 4;
  f32x4 acc[2][4];
#pragma unroll
  for (int i = 0; i < 2; ++i)
#pragma unroll
    for (int g = 0; g < 4; ++g)
#pragma unroll
      for (int rg = 0; rg < 4; ++rg)
        acc[i][g][rg] = bl[(2*wv + i)*16 + lk*4 + rg];
#pragma unroll
  for (int ch = 0; ch < 2; ++ch) {
    int slx = ((ch*4 + lk) ^ (ln & 7)) << 3;
    short8 a0 = *(const short8*)&wA[((2*wv + 0)*16 + ln)*64 + slx];
    short8 a1 = *(const short8*)&wA[((2*wv + 1)*16 + ln)*64 + slx];
#pragma unroll
    for (int g = 0; g < 4; ++g) {
      short8 bv = *(const short8*)&lnb[(g*16 + ln)*64 + slx];
      acc[0][g] = __builtin_amdgcn_mfma_f32_16x16x32_bf16(a0, bv, acc[0][g], 0, 0, 0);
      acc[1][g] = __builtin_amdgcn_mfma_f32_16x16x32_bf16(a1, bv, acc[1][g], 0, 0, 0);
    }
  }
  // D -> LDS stage (swizzled 8B granules), then coalesced copy-out
  u16t* stg = (u16t*)xl;   // 64px x 128oc bf16 = 16KB
#pragma unroll
  for (int i = 0; i < 2; ++i)
#pragma unroll
    for (int g = 0; g < 4; ++g) {
      int pxd = g*16 + ln;
      int g8 = (2*wv + i)*4 + lk;             // oc>>2
      int st = g8 ^ (pxd & 15);
      *(uint2*)&stg[pxd*128 + (st << 2)] =
          make_uint2(pk2(acc[i][g][0], acc[i][g][1]), pk2(acc[i][g][2], acc[i][g][3]));
    }
  __syncthreads();
  bf16* xp = x1 + (((size_t)b*HH + h)*WW + w0)*128;
  for (int j = t; j < 2048; j += 256) {
    int pxd = j >> 5, gs = j & 31;
    uint2 val = *(uint2*)&stg[pxd*128 + (gs << 2)];
    *(uint2*)(xp + (size_t)pxd*128 + ((gs ^ (pxd & 15)) << 2)) = val;
  }
}

// ---------------- conv2 via MFMA implicit GEMM + SG + pool ----------------
// grid = 2304 blocks, 256 threads (4 waves). LDS ~67.5 KB -> 2 blocks/CU.
// K split into 2 ic-halves of 64; acc persists across halves.
__global__ __launch_bounds__(256) void k_conv2m(
    const bf16* __restrict__ x1, const bf16* __restrict__ aw2,
    const float* __restrict__ ab2, bf16* __restrict__ kx, float* __restrict__ pool) {
  __shared__ alignas(16) u16t xs[4*66*64];      // 33792 B; reused as kx stage
  __shared__ alignas(16) u16t wsA[8192];        // 16 KB
  __shared__ alignas(16) u16t wsB[8192];        // 16 KB
  __shared__ float pool_l[64];
  __shared__ float bias_l[128];
  int bid = blockIdx.x;
  int n = bid >> 5, rp = bid & 31;
  int b = n / 36, ph = (n % 36) / 6, pw = n % 6;
  int r0 = rp * 2;
  int t = threadIdx.x;
  if (t < 64) pool_l[t] = 0.f;
  if (t < 128) bias_l[t] = ab2[n*128 + t];

  const bf16* xbase = x1 + ((((size_t)b*HH + ph*64)*WW + pw*64) << 7);
  const bf16* wbase = aw2 + (size_t)n*147456;
  int wv = t >> 6, l = t & 63;
  int ln = l & 15, lk = l >> 4;
  int rr = wv >> 1;
  int cb0 = (wv & 1) * 32;
  f32x4 acc[8][2];
#pragma unroll
  for (int f = 0; f < 8; ++f)
#pragma unroll
    for (int g = 0; g < 2; ++g) acc[f][g] = (f32x4){0.f, 0.f, 0.f, 0.f};

  for (int icc = 0; icc < 2; ++icc) {
    __syncthreads();   // prior-half xs/wsA readers done before restage
    // stage xs half: 4 rows x 66 cols x 64 ic (slot8 ^ (c&7) swizzle)
    for (int j = t; j < 2112; j += 256) {
      int s_st = j & 7;
      int rc = j >> 3;
      int c = rc % 66, r = rc / 66;
      int gr = r0 + r - 1, gc = c - 1;
      uint4 val = make_uint4(0u, 0u, 0u, 0u);
      if (gr >= 0 && gr < 64 && gc >= 0 && gc < 64) {
        int s_orig = s_st ^ (c & 7);
        val = *(const uint4*)(xbase + (((size_t)gr*WW + gc) << 7) + icc*64 + s_orig*8);
      }
      *(uint4*)&xs[j*8] = val;
    }
    // stage ws[pos=0][icc]
    {
      const uint4* wp = (const uint4*)(wbase + (size_t)icc*8192);
#pragma unroll
      for (int i = 0; i < 4; ++i) ((uint4*)wsA)[i*256 + t] = wp[i*256 + t];
    }
    __syncthreads();

    uint4 stgld[4];
    for (int pos = 0; pos < 9; ++pos) {
      const u16t* wcur = (pos & 1) ? wsB : wsA;
      u16t* wnx = (pos & 1) ? wsA : wsB;
      int dh = pos / 3, dw = pos - dh*3;
      if (pos < 8) {
        const uint4* wp = (const uint4*)(wbase + (size_t)((pos + 1)*2 + icc)*8192);
#pragma unroll
        for (int i = 0; i < 4; ++i) stgld[i] = wp[i*256 + t];
      }
#pragma unroll
      for (int ch = 0; ch < 2; ++ch) {
        short8 af[8];
#pragma unroll
        for (int f = 0; f < 8; ++f) {
          int oc = f*16 + ln;
          int slot = (ch*4 + lk) ^ (oc & 7);
          af[f] = *(const short8*)&wcur[oc*64 + slot*8];
        }
#pragma unroll
        for (int g = 0; g < 2; ++g) {
          int cl = cb0 + g*16 + ln + dw;
          int row = rr + dh;
          int slot = (ch*4 + lk) ^ (cl & 7);
          short8 bfv = *(const short8*)&xs[(row*66 + cl)*64 + slot*8];
#pragma unroll
          for (int f = 0; f < 8; ++f)
            acc[f][g] = __builtin_amdgcn_mfma_f32_16x16x32_bf16(af[f], bfv, acc[f][g], 0, 0, 0);
        }
      }
      if (pos < 8) {
#pragma unroll
        for (int i = 0; i < 4; ++i) *(uint4*)&wnx[(i*256 + t)*8] = stgld[i];
        __syncthreads();   // wnx last read at pos-1 (before this point); safe
      }
    }
  }

  __syncthreads();                 // all xs reads done -> reuse xs as stage
  u16t* stg = xs;                  // [2 rows][64 cols][64 q] bf16 = 16KB
  float psum[4][4];
#pragma unroll
  for (int f = 0; f < 4; ++f)
#pragma unroll
    for (int rg = 0; rg < 4; ++rg) psum[f][rg] = 0.f;
#pragma unroll
  for (int f = 0; f < 4; ++f) {
#pragma unroll
    for (int g = 0; g < 2; ++g) {
      f32x4 lo = acc[f][g], hi = acc[f + 4][g];
      int col = cb0 + g*16 + ln;
      float kv[4];
#pragma unroll
      for (int rg = 0; rg < 4; ++rg) {
        int q = f*16 + lk*4 + rg;
        kv[rg] = (lo[rg] + bias_l[q]) * (hi[rg] + bias_l[64 + q]);
        psum[f][rg] += kv[rg];
      }
      int gq = f*4 + lk;
      int st = gq ^ (col & 15);
      *(uint2*)&stg[rr*4096 + col*64 + (st << 2)] =
          make_uint2(pk2(kv[0], kv[1]), pk2(kv[2], kv[3]));
    }
  }
#pragma unroll
  for (int f = 0; f < 4; ++f)
#pragma unroll
    for (int rg = 0; rg < 4; ++rg) {
      float s = psum[f][rg];
      s += __shfl_xor(s, 1); s += __shfl_xor(s, 2);
      s += __shfl_xor(s, 4); s += __shfl_xor(s, 8);
      if (ln == 0) atomicAdd(&pool_l[f*16 + lk*4 + rg], s);
    }
  __syncthreads();
  for (int j = t; j < 2048; j += 256) {
    int rr2 = j >> 10, remj = j & 1023, col = remj >> 4, gs = remj & 15;
    uint2 val = *(uint2*)&stg[rr2*4096 + col*64 + (gs << 2)];
    int hh2 = ph*64 + r0 + rr2;
    int gcol = pw*64 + col;
    *(uint2*)(kx + ((((size_t)b*HH + hh2)*WW + gcol) << 6) + ((gs ^ (col & 15)) << 2)) = val;
  }
  if (t < 64) atomicAdd(&pool[b*64 + t], pool_l[t]);
}

// ---------------- fused post (MFMA): sca, pool-mul, w3, y=inp+x*beta (regs),
//                  LN2, w4, SG, w5, out = y + x*gamma ----------------
// grid 4608, 256 threads. No yws round-trip.
__global__ __launch_bounds__(256) void k_post(
    const bf16* __restrict__ kxg, const float* __restrict__ inp,
    const float* __restrict__ pool,
    const bf16* __restrict__ ascab, const float* __restrict__ abscaf,
    const bf16* __restrict__ a3b, const float* __restrict__ ab3,
    const float* __restrict__ beta,
    const bf16* __restrict__ a4b, const float* __restrict__ ab4,
    const bf16* __restrict__ a5b, const float* __restrict__ ab5,
    const float* __restrict__ n2w, const float* __restrict__ n2b,
    const float* __restrict__ gamma, float* __restrict__ outp) {
  __shared__ alignas(16) u16t wS[4096];
  __shared__ alignas(16) u16t w3S[4096];
  __shared__ alignas(16) u16t w4S[8192];
  __shared__ alignas(16) u16t w5S[4096];
  __shared__ alignas(16) u16t B1[4096];
  __shared__ alignas(16) u16t B2[4096];
  __shared__ alignas(16) u16t pxb[4096];
  __shared__ float ps[4][64], ps2[4][64];
  __shared__ float bsl[64], b3l[64], pol[64], betal[64];
  __shared__ float b4l[128], b5l[64], gl[64], bel[64], gml[64];
  int bid = blockIdx.x;
  int b = bid / 2304; int rem = bid % 2304; int h = rem / 6; int pw = rem % 6;
  int ph = h >> 6; int n = (b*6 + ph)*6 + pw; int w0 = pw*64;
  int t = threadIdx.x;
  for (int j = t; j < 512; j += 256) {
    ((uint4*)wS)[j]  = ((const uint4*)(ascab + (size_t)n*4096))[j];
    ((uint4*)w3S)[j] = ((const uint4*)(a3b + (size_t)n*4096))[j];
    ((uint4*)w5S)[j] = ((const uint4*)(a5b + (size_t)n*4096))[j];
  }
  for (int j = t; j < 1024; j += 256)
    ((uint4*)w4S)[j] = ((const uint4*)(a4b + (size_t)n*8192))[j];
  if (t < 128) b4l[t] = ab4[n*128 + t];
  if (t < 64) {
    bsl[t] = abscaf[n*64 + t];
    b3l[t] = ab3[n*64 + t];
    pol[t] = pool[b*64 + t] * (1.0f/147456.0f);
    betal[t] = beta[t];
    b5l[t] = ab5[n*64 + t];
    gl[t]  = n2w[t];
    bel[t] = n2b[t];
    gml[t] = gamma[t];
  }
  const bf16* kxp = kxg + (((size_t)b*HH + h)*WW + w0)*64;
  for (int j = t; j < 512; j += 256) {
    int px = j >> 3, sl = j & 7;
    *(uint4*)&B1[px*64 + ((sl ^ (px & 7)) << 3)] = *(const uint4*)(kxp + px*64 + sl*8);
  }
  __syncthreads();
  int wv = t >> 6, l = t & 63, ln = l & 15, lk = l >> 4;
  // GEMM1: sca
  f32x4 acc[4];
#pragma unroll
  for (int g = 0; g < 4; ++g)
#pragma unroll
    for (int rg = 0; rg < 4; ++rg) acc[g][rg] = bsl[wv*16 + lk*4 + rg];
#pragma unroll
  for (int ch = 0; ch < 2; ++ch) {
    int slx = ((ch*4 + lk) ^ (ln & 7)) << 3;
    short8 a = *(const short8*)&wS[(wv*16 + ln)*64 + slx];
#pragma unroll
    for (int g = 0; g < 4; ++g) {
      short8 bv = *(const short8*)&B1[(g*16 + ln)*64 + slx];
      acc[g] = __builtin_amdgcn_mfma_f32_16x16x32_bf16(a, bv, acc[g], 0, 0, 0);
    }
  }
  // scale by pooled mean, write B2 (swizzled)
#pragma unroll
  for (int g = 0; g < 4; ++g) {
    int px = g*16 + ln;
    float vv[4];
#pragma unroll
    for (int rg = 0; rg < 4; ++rg) vv[rg] = acc[g][rg] * pol[wv*16 + lk*4 + rg];
    int base = px*64 + (((2*wv + (lk >> 1)) ^ (px & 7)) << 3) + (lk & 1)*4;
    *(uint2*)&B2[base] = make_uint2(pk2(vv[0], vv[1]), pk2(vv[2], vv[3]));
  }
  __syncthreads();
  // GEMM2: w3 -> x frags
  f32x4 acc2[4];
#pragma unroll
  for (int g = 0; g < 4; ++g)
#pragma unroll
    for (int rg = 0; rg < 4; ++rg) acc2[g][rg] = b3l[wv*16 + lk*4 + rg];
#pragma unroll
  for (int ch = 0; ch < 2; ++ch) {
    int slx = ((ch*4 + lk) ^ (ln & 7)) << 3;
    short8 a = *(const short8*)&w3S[(wv*16 + ln)*64 + slx];
#pragma unroll
    for (int g = 0; g < 4; ++g) {
      short8 bv = *(const short8*)&B2[(g*16 + ln)*64 + slx];
      acc2[g] = __builtin_amdgcn_mfma_f32_16x16x32_bf16(a, bv, acc2[g], 0, 0, 0);
    }
  }
  // y = inp + x*beta, kept in registers
  const float* inpp = inp + ((size_t)b*64*HH + h)*WW + w0;
  float yv[4][4];
#pragma unroll
  for (int g = 0; g < 4; ++g) {
    int px = g*16 + ln;
#pragma unroll
    for (int rg = 0; rg < 4; ++rg) {
      int oc = wv*16 + lk*4 + rg;
      yv[g][rg] = inpp[(size_t)oc*HWH + px] + acc2[g][rg]*betal[oc];
    }
  }
  // LN2 stats: per pixel, sum over channels. Each lane has 4 ch per g;
  // shfl over lk (lanes +-16,32) -> wave partial (16 ch), then LDS 4-way.
#pragma unroll
  for (int g = 0; g < 4; ++g) {
    float s = yv[g][0] + yv[g][1] + yv[g][2] + yv[g][3];
    float s2 = yv[g][0]*yv[g][0] + yv[g][1]*yv[g][1]
             + yv[g][2]*yv[g][2] + yv[g][3]*yv[g][3];
    s += __shfl_xor(s, 16); s += __shfl_xor(s, 32);
    s2 += __shfl_xor(s2, 16); s2 += __shfl_xor(s2, 32);
    if (lk == 0) { ps[wv][g*16 + ln] = s; ps2[wv][g*16 + ln] = s2; }
  }
  __syncthreads();
  // LN out -> pxb (bf16, swizzled), per thread's own (pixel, 4ch) quads
#pragma unroll
  for (int g = 0; g < 4; ++g) {
    int pxd = g*16 + ln;
    float mu = (ps[0][pxd] + ps[1][pxd] + ps[2][pxd] + ps[3][pxd]) * (1.f/64.f);
    float var = (ps2[0][pxd] + ps2[1][pxd] + ps2[2][pxd] + ps2[3][pxd]) * (1.f/64.f) - mu*mu;
    float rs = rsqrtf(fmaxf(var, 0.f) + EPSV);
    float lv[4];
#pragma unroll
    for (int rg = 0; rg < 4; ++rg) {
      int oc = wv*16 + lk*4 + rg;
      lv[rg] = (yv[g][rg] - mu) * rs * gl[oc] + bel[oc];
    }
    int base = pxd*64 + (((2*wv + (lk >> 1)) ^ (pxd & 7)) << 3) + (lk & 1)*4;
    *(uint2*)&pxb[base] = make_uint2(pk2(lv[0], lv[1]), pk2(lv[2], lv[3]));
  }
  __syncthreads();
  // w4 GEMM: wave owns oc-frags {wv, wv+4} so SG pairs share a lane
  f32x4 accL[4], accH[4];
#pragma unroll
  for (int g = 0; g < 4; ++g)
#pragma unroll
    for (int rg = 0; rg < 4; ++rg) {
      accL[g][rg] = b4l[wv*16 + lk*4 + rg];
      accH[g][rg] = b4l[64 + wv*16 + lk*4 + rg];
    }
#pragma unroll
  for (int ch = 0; ch < 2; ++ch) {
    int slx = ((ch*4 + lk) ^ (ln & 7)) << 3;
    short8 aLo = *(const short8*)&w4S[((wv)*16 + ln)*64 + slx];
    short8 aHi = *(const short8*)&w4S[((wv + 4)*16 + ln)*64 + slx];
#pragma unroll
    for (int g = 0; g < 4; ++g) {
      short8 bv = *(const short8*)&pxb[(g*16 + ln)*64 + slx];
      accL[g] = __builtin_amdgcn_mfma_f32_16x16x32_bf16(aLo, bv, accL[g], 0, 0, 0);
      accH[g] = __builtin_amdgcn_mfma_f32_16x16x32_bf16(aHi, bv, accH[g], 0, 0, 0);
    }
  }
  __syncthreads();          // all w4 reads of pxb done
  // SimpleGate -> pxb (swizzled)
#pragma unroll
  for (int g = 0; g < 4; ++g) {
    int pxd = g*16 + ln;
    float vv[4];
#pragma unroll
    for (int rg = 0; rg < 4; ++rg) vv[rg] = accL[g][rg] * accH[g][rg];
    int base = pxd*64 + (((2*wv + (lk >> 1)) ^ (pxd & 7)) << 3) + (lk & 1)*4;
    *(uint2*)&pxb[base] = make_uint2(pk2(vv[0], vv[1]), pk2(vv[2], vv[3]));
  }
  __syncthreads();
  // w5 GEMM
  f32x4 acc5[4];
#pragma unroll
  for (int g = 0; g < 4; ++g)
#pragma unroll
    for (int rg = 0; rg < 4; ++rg) acc5[g][rg] = b5l[wv*16 + lk*4 + rg];
#pragma unroll
  for (int ch = 0; ch < 2; ++ch) {
    int slx = ((ch*4 + lk) ^ (ln & 7)) << 3;
    short8 a = *(const short8*)&w5S[(wv*16 + ln)*64 + slx];
#pragma unroll
    for (int g = 0; g < 4; ++g) {
      short8 bv = *(const short8*)&pxb[(g*16 + ln)*64 + slx];
      acc5[g] = __builtin_amdgcn_mfma_f32_16x16x32_bf16(a, bv, acc5[g], 0, 0, 0);
    }
  }
  float* op = outp + ((size_t)b*64*HH + h)*WW + w0;
#pragma unroll
  for (int g = 0; g < 4; ++g) {
    int pxd = g*16 + ln;
#pragma unroll
    for (int rg = 0; rg < 4; ++rg) {
      int oc = wv*16 + lk*4 + rg;
      op[(size_t)oc*HWH + pxd] = yv[g][rg] + acc5[g][rg]*gml[oc];
    }
  }
}

extern "C" void kernel_launch(void* const* d_in, const int* in_sizes, int n_in,
                              void* d_out, int out_size, void* d_ws, size_t ws_size,
                              hipStream_t stream) {
  (void)in_sizes; (void)n_in; (void)out_size; (void)ws_size;
  const float* inp  = (const float*)d_in[0];
  const float* v    = (const float*)d_in[1];
  const float* w1   = (const float*)d_in[2];
  const float* b1   = (const float*)d_in[3];
  const float* w2   = (const float*)d_in[4];
  const float* b2   = (const float*)d_in[5];
  const float* w3   = (const float*)d_in[6];
  const float* b3   = (const float*)d_in[7];
  const float* wsca = (const float*)d_in[8];
  const float* bsca = (const float*)d_in[9];
  const float* w4   = (const float*)d_in[10];
  const float* b4   = (const float*)d_in[11];
  const float* w5   = (const float*)d_in[12];
  const float* b5   = (const float*)d_in[13];
  const float* n1w  = (const float*)d_in[14];
  const float* n1b  = (const float*)d_in[15];
  const float* n2w  = (const float*)d_in[16];
  const float* n2b  = (const float*)d_in[17];
  const float* beta = (const float*)d_in[18];
  const float* gamma= (const float*)d_in[19];

  // ws layout: f32 biases+pool, then bf16 weights/activations (~139 MB)
  float* wsf  = (float*)d_ws;
  float* pool = wsf;                    // [2][64]
  float* ab1  = wsf + 128;              // [72][128]
  float* ab2  = ab1 + 9216;
  float* ab4  = ab2 + 9216;
  float* abscaf = ab4 + 9216;           // [72][64]
  float* ab3  = abscaf + 4608;
  float* ab5  = ab3 + 4608;
  bf16* aw1b  = (bf16*)(ab5 + 4608);    // [72][128][64] swz
  bf16* a4b   = aw1b + 589824;          // [72][128][64] swz
  bf16* ascab = a4b + 589824;           // [72][64][64] swz
  bf16* a3b   = ascab + 294912;
  bf16* a5b   = a3b + 294912;
  bf16* aw2   = a5b + 294912;           // [72][9][2][128][64] swz
  bf16* x1    = aw2 + 10616832;         // [2][384][384][128] pixel-major
  bf16* kxb   = x1 + 37748736;          // [2][384][384][64] pixel-major
  float* out0 = (float*)d_out;

  hipMemsetAsync(pool, 0, 128*sizeof(float), stream);
  k_prep<<<dim3(576), dim3(256), 0, stream>>>(v, w1, b1, w2, b2, w3, b3, wsca, bsca,
      w4, b4, w5, b5, aw1b, a4b, ascab, a3b, a5b, ab1, ab2, ab4, abscaf, ab3, ab5, aw2);
  k_ln_conv1<<<dim3(4608), dim3(256), 0, stream>>>(inp, aw1b, ab1, n1w, n1b, x1);
  k_conv2m<<<dim3(2304), dim3(256), 0, stream>>>(x1, aw2, ab2, kxb, pool);
  k_post<<<dim3(4608), dim3(256), 0, stream>>>(kxb, inp, pool, ascab, abscaf, a3b, ab3,
      beta, a4b, ab4, a5b, ab5, n2w, n2b, gamma, out0);
  hipMemcpyAsync((char*)d_out + (size_t)18874368*4, d_in[1], 360*4,
                 hipMemcpyDeviceToDevice, stream);
}